// Round 2
// baseline (1165.885 us; speedup 1.0000x reference)
//
#include <hip/hip_runtime.h>
#include <hip/hip_bf16.h>

typedef __attribute__((ext_vector_type(8))) __bf16 bf16x8;
typedef __attribute__((ext_vector_type(4))) float f32x4;

#define IN_CH 512
#define OUT_CH 64
#define WT_STRIDE 520   // 512 + 8 bf16 pad
#define BS 196          // rows per bucket (rowres fits in 8 bits)
#define NB 256          // buckets; BS*NB = 50176 >= N
#define CHUNK 2048      // edges per scatter block (256 thr x 8)

// ---------------- GEMM: base = features @ W (bf16 MFMA, fp32 accum) ----------
__global__ __launch_bounds__(256) void gemm_kernel(
    const float* __restrict__ A, const float* __restrict__ W,
    float* __restrict__ out, int N)
{
    __shared__ __align__(16) __bf16 Wt[OUT_CH * WT_STRIDE];

    const int tid = threadIdx.x;
    for (int idx = tid; idx < IN_CH * OUT_CH; idx += 256) {
        int k = idx >> 6, n = idx & 63;
        Wt[n * WT_STRIDE + k] = (__bf16)W[idx];
    }
    __syncthreads();

    const int lane = tid & 63;
    const int wave = tid >> 6;
    const int row0 = blockIdx.x * 64 + wave * 16;
    int row_a = row0 + (lane & 15);
    int row_c = row_a < N ? row_a : N - 1;

    const float* arow = A + (size_t)row_c * IN_CH;
    const int kg = (lane >> 4) * 8;
    const int col = lane & 15;

    f32x4 acc0 = {0.f,0.f,0.f,0.f}, acc1 = {0.f,0.f,0.f,0.f};
    f32x4 acc2 = {0.f,0.f,0.f,0.f}, acc3 = {0.f,0.f,0.f,0.f};

    for (int ks = 0; ks < IN_CH / 32; ++ks) {
        int kb = ks * 32 + kg;
        float4 p = *(const float4*)(arow + kb);
        float4 q = *(const float4*)(arow + kb + 4);
        bf16x8 a;
        a[0]=(__bf16)p.x; a[1]=(__bf16)p.y; a[2]=(__bf16)p.z; a[3]=(__bf16)p.w;
        a[4]=(__bf16)q.x; a[5]=(__bf16)q.y; a[6]=(__bf16)q.z; a[7]=(__bf16)q.w;
        bf16x8 b0 = *(const bf16x8*)(&Wt[(col     ) * WT_STRIDE + kb]);
        bf16x8 b1 = *(const bf16x8*)(&Wt[(col + 16) * WT_STRIDE + kb]);
        bf16x8 b2 = *(const bf16x8*)(&Wt[(col + 32) * WT_STRIDE + kb]);
        bf16x8 b3 = *(const bf16x8*)(&Wt[(col + 48) * WT_STRIDE + kb]);
        acc0 = __builtin_amdgcn_mfma_f32_16x16x32_bf16(a, b0, acc0, 0, 0, 0);
        acc1 = __builtin_amdgcn_mfma_f32_16x16x32_bf16(a, b1, acc1, 0, 0, 0);
        acc2 = __builtin_amdgcn_mfma_f32_16x16x32_bf16(a, b2, acc2, 0, 0, 0);
        acc3 = __builtin_amdgcn_mfma_f32_16x16x32_bf16(a, b3, acc3, 0, 0, 0);
    }

    int rr = row0 + (lane >> 4) * 4;
    for (int i = 0; i < 4; ++i) {
        int r = rr + i;
        if (r < N) {
            float* o = out + (size_t)r * OUT_CH;
            o[col]      = acc0[i];
            o[col + 16] = acc1[i];
            o[col + 32] = acc2[i];
            o[col + 48] = acc3[i];
        }
    }
}

// ---------------- bucket count ----------------------------------------------
__global__ __launch_bounds__(256) void count_kernel(
    const int* __restrict__ rows, int* __restrict__ bcnt, int E)
{
    __shared__ int hist[NB];
    const int tid = threadIdx.x;
    hist[tid] = 0;
    __syncthreads();
    for (int e = blockIdx.x * blockDim.x + tid; e < E; e += gridDim.x * blockDim.x) {
        int b = rows[e] / BS;   // compile-time divisor -> magic mul
        atomicAdd(&hist[b], 1);
    }
    __syncthreads();
    if (hist[tid]) atomicAdd(&bcnt[tid], hist[tid]);
}

// ---------------- 256-wide exclusive scan ------------------------------------
__global__ __launch_bounds__(256) void scan_kernel(
    const int* __restrict__ bcnt, int* __restrict__ bbase, int* __restrict__ bcur)
{
    __shared__ int lds[NB];
    const int t = threadIdx.x;
    int v = bcnt[t];
    lds[t] = v;
    __syncthreads();
    for (int ofs = 1; ofs < NB; ofs <<= 1) {
        int u = 0;
        if (t >= ofs) u = lds[t - ofs];
        __syncthreads();
        if (t >= ofs) lds[t] += u;
        __syncthreads();
    }
    int excl = lds[t] - v;
    bbase[t] = excl;
    bcur[t]  = excl;
    if (t == NB - 1) bbase[NB] = lds[NB - 1];
}

// ---------------- bucket scatter: group 2048 edges per block -----------------
__global__ __launch_bounds__(256) void bucket_scatter_kernel(
    const int* __restrict__ rows, const int* __restrict__ cols,
    const float* __restrict__ vals, int* __restrict__ bcur,
    int2* __restrict__ seg, int E)
{
    __shared__ int hist[NB];
    __shared__ int posBase[NB];
    const int tid = threadIdx.x;
    const int c0 = blockIdx.x * CHUNK;

    hist[tid] = 0;
    __syncthreads();

    int myb[8], mypack[8]; float myval[8];
    #pragma unroll
    for (int i = 0; i < 8; ++i) {
        int e = c0 + i * 256 + tid;
        myb[i] = -1;
        if (e < E) {
            int r = rows[e];
            int b = r / BS;
            int rr = r - b * BS;
            myb[i] = b;
            mypack[i] = (cols[e] << 8) | rr;
            myval[i] = vals[e];
            atomicAdd(&hist[b], 1);
        }
    }
    __syncthreads();

    int h = hist[tid];
    if (h) posBase[tid] = atomicAdd(&bcur[tid], h);
    hist[tid] = 0;   // reuse as local cursor
    __syncthreads();

    #pragma unroll
    for (int i = 0; i < 8; ++i) {
        if (myb[i] >= 0) {
            int p = posBase[myb[i]] + atomicAdd(&hist[myb[i]], 1);
            int2 cv; cv.x = mypack[i]; cv.y = __float_as_int(myval[i]);
            seg[p] = cv;
        }
    }
}

// ---------------- SpMM by bucket: LDS accumulators ---------------------------
__global__ __launch_bounds__(1024) void spmm_bucket_kernel(
    const int* __restrict__ bbase, const int2* __restrict__ seg,
    const float* __restrict__ x, float* __restrict__ y,
    const float* __restrict__ bias, int N)
{
    __shared__ float ylds[BS * OUT_CH];   // 49 KB

    const int tid = threadIdx.x;
    const int b = blockIdx.x;
    for (int i = tid; i < BS * OUT_CH; i += 1024) ylds[i] = 0.f;
    __syncthreads();

    const int s = bbase[b];
    const int e = bbase[b + 1];
    const int lane = tid & 63;
    const int wv = tid >> 6;   // 16 waves

    int i = s + wv;
    int2 cv;
    if (i < e) cv = seg[i];
    while (i < e) {
        int nxt = i + 16;
        int2 cvn;
        if (nxt < e) cvn = seg[nxt];
        int packed = cv.x;
        float v = __int_as_float(cv.y);
        int col = ((unsigned)packed) >> 8;
        int rr = packed & 255;
        float xv = x[(size_t)col * OUT_CH + lane];
        atomicAdd(&ylds[rr * OUT_CH + lane], v * xv);
        cv = cvn;
        i = nxt;
    }
    __syncthreads();

    const int rowBase = b * BS;
    for (int idx = tid; idx < BS * OUT_CH; idx += 1024) {
        int r = rowBase + (idx >> 6);
        if (r < N) {
            float o = ylds[idx];
            if (bias) o += bias[idx & 63];
            y[(size_t)r * OUT_CH + (idx & 63)] = o;
        }
    }
}

// ---------------- launch -----------------------------------------------------
static inline size_t align_up(size_t v) { return (v + 255) & ~(size_t)255; }

extern "C" void kernel_launch(void* const* d_in, const int* in_sizes, int n_in,
                              void* d_out, int out_size, void* d_ws, size_t ws_size,
                              hipStream_t stream)
{
    const int*   adj  = (const int*)d_in[0];    // [2,E]
    const float* vals = (const float*)d_in[1];  // [E]
    const float* feat = (const float*)d_in[2];  // [N,512]
    const float* Wm   = (const float*)d_in[3];  // [512,64]
    const float* bias = (const float*)d_in[4];  // [64]

    const int E = in_sizes[1];
    const int N = in_sizes[2] / IN_CH;
    const int* rows  = adj;
    const int* colsI = adj + E;

    char* w = (char*)d_ws;
    size_t o = 0;
    float* B0    = (float*)(w + o); o += align_up((size_t)N * OUT_CH * sizeof(float));
    float* Y1    = (float*)(w + o); o += align_up((size_t)N * OUT_CH * sizeof(float));
    int*   bcnt  = (int*)  (w + o); o += align_up(NB * sizeof(int));
    int*   bbase = (int*)  (w + o); o += align_up((NB + 1) * sizeof(int));
    int*   bcur  = (int*)  (w + o); o += align_up(NB * sizeof(int));
    int2*  seg   = (int2*) (w + o); o += align_up((size_t)E * sizeof(int2));
    (void)ws_size; (void)n_in; (void)out_size;

    // 1. dense projection -> B0
    gemm_kernel<<<(N + 63) / 64, 256, 0, stream>>>(feat, Wm, B0, N);

    // 2. bucket the edges (no per-row CSR)
    hipMemsetAsync(bcnt, 0, NB * sizeof(int), stream);
    count_kernel<<<1024, 256, 0, stream>>>(rows, bcnt, E);
    scan_kernel<<<1, 256, 0, stream>>>(bcnt, bbase, bcur);
    bucket_scatter_kernel<<<(E + CHUNK - 1) / CHUNK, 256, 0, stream>>>(
        rows, colsI, vals, bcur, seg, E);

    // 3. two propagation rounds (bias fused into the last)
    spmm_bucket_kernel<<<NB, 1024, 0, stream>>>(bbase, seg, B0, Y1, nullptr, N);
    spmm_bucket_kernel<<<NB, 1024, 0, stream>>>(bbase, seg, Y1, (float*)d_out, bias, N);
}

// Round 3
// 1141.267 us; speedup vs baseline: 1.0216x; 1.0216x over previous
//
#include <hip/hip_runtime.h>
#include <hip/hip_bf16.h>

typedef __attribute__((ext_vector_type(8))) __bf16 bf16x8;
typedef __attribute__((ext_vector_type(4))) float f32x4;

#define IN_CH 512
#define OUT_CH 64
#define WT_STRIDE 520   // 512 + 8 bf16 pad
#define BS 98           // rows per bucket (rowres fits in 8 bits)
#define NB 512          // buckets; BS*NB = 50176 >= N
#define CHUNK 4096      // edges per scatter block (512 thr x 8)

// ---------------- GEMM: base = features @ W (bf16 MFMA, fp32 accum) ----------
__global__ __launch_bounds__(256) void gemm_kernel(
    const float* __restrict__ A, const float* __restrict__ W,
    float* __restrict__ out, int N)
{
    __shared__ __align__(16) __bf16 Wt[OUT_CH * WT_STRIDE];

    const int tid = threadIdx.x;
    for (int idx = tid; idx < IN_CH * OUT_CH; idx += 256) {
        int k = idx >> 6, n = idx & 63;
        Wt[n * WT_STRIDE + k] = (__bf16)W[idx];
    }
    __syncthreads();

    const int lane = tid & 63;
    const int wave = tid >> 6;
    const int row0 = blockIdx.x * 64 + wave * 16;
    int row_a = row0 + (lane & 15);
    int row_c = row_a < N ? row_a : N - 1;

    const float* arow = A + (size_t)row_c * IN_CH;
    const int kg = (lane >> 4) * 8;
    const int col = lane & 15;

    f32x4 acc0 = {0.f,0.f,0.f,0.f}, acc1 = {0.f,0.f,0.f,0.f};
    f32x4 acc2 = {0.f,0.f,0.f,0.f}, acc3 = {0.f,0.f,0.f,0.f};

    for (int ks = 0; ks < IN_CH / 32; ++ks) {
        int kb = ks * 32 + kg;
        float4 p = *(const float4*)(arow + kb);
        float4 q = *(const float4*)(arow + kb + 4);
        bf16x8 a;
        a[0]=(__bf16)p.x; a[1]=(__bf16)p.y; a[2]=(__bf16)p.z; a[3]=(__bf16)p.w;
        a[4]=(__bf16)q.x; a[5]=(__bf16)q.y; a[6]=(__bf16)q.z; a[7]=(__bf16)q.w;
        bf16x8 b0 = *(const bf16x8*)(&Wt[(col     ) * WT_STRIDE + kb]);
        bf16x8 b1 = *(const bf16x8*)(&Wt[(col + 16) * WT_STRIDE + kb]);
        bf16x8 b2 = *(const bf16x8*)(&Wt[(col + 32) * WT_STRIDE + kb]);
        bf16x8 b3 = *(const bf16x8*)(&Wt[(col + 48) * WT_STRIDE + kb]);
        acc0 = __builtin_amdgcn_mfma_f32_16x16x32_bf16(a, b0, acc0, 0, 0, 0);
        acc1 = __builtin_amdgcn_mfma_f32_16x16x32_bf16(a, b1, acc1, 0, 0, 0);
        acc2 = __builtin_amdgcn_mfma_f32_16x16x32_bf16(a, b2, acc2, 0, 0, 0);
        acc3 = __builtin_amdgcn_mfma_f32_16x16x32_bf16(a, b3, acc3, 0, 0, 0);
    }

    int rr = row0 + (lane >> 4) * 4;
    for (int i = 0; i < 4; ++i) {
        int r = rr + i;
        if (r < N) {
            float* o = out + (size_t)r * OUT_CH;
            o[col]      = acc0[i];
            o[col + 16] = acc1[i];
            o[col + 32] = acc2[i];
            o[col + 48] = acc3[i];
        }
    }
}

// ---------------- bucket count ----------------------------------------------
__global__ __launch_bounds__(512) void count_kernel(
    const int* __restrict__ rows, int* __restrict__ bcnt, int E)
{
    __shared__ int hist[NB];
    const int tid = threadIdx.x;
    hist[tid] = 0;
    __syncthreads();
    for (int e = blockIdx.x * blockDim.x + tid; e < E; e += gridDim.x * blockDim.x) {
        int b = rows[e] / BS;
        atomicAdd(&hist[b], 1);
    }
    __syncthreads();
    if (hist[tid]) atomicAdd(&bcnt[tid], hist[tid]);
}

// ---------------- NB-wide exclusive scan -------------------------------------
__global__ __launch_bounds__(NB) void scan_kernel(
    const int* __restrict__ bcnt, int* __restrict__ bbase, int* __restrict__ bcur)
{
    __shared__ int lds[NB];
    const int t = threadIdx.x;
    int v = bcnt[t];
    lds[t] = v;
    __syncthreads();
    for (int ofs = 1; ofs < NB; ofs <<= 1) {
        int u = 0;
        if (t >= ofs) u = lds[t - ofs];
        __syncthreads();
        if (t >= ofs) lds[t] += u;
        __syncthreads();
    }
    int excl = lds[t] - v;
    bbase[t] = excl;
    bcur[t]  = excl;
    if (t == NB - 1) bbase[NB] = lds[NB - 1];
}

// ---------------- bucket scatter: group 4096 edges per block -----------------
__global__ __launch_bounds__(512) void bucket_scatter_kernel(
    const int* __restrict__ rows, const int* __restrict__ cols,
    const float* __restrict__ vals, int* __restrict__ bcur,
    int2* __restrict__ seg, int E)
{
    __shared__ int hist[NB];
    __shared__ int posBase[NB];
    const int tid = threadIdx.x;
    const int c0 = blockIdx.x * CHUNK;

    hist[tid] = 0;
    __syncthreads();

    int myb[8], mypack[8]; float myval[8];
    #pragma unroll
    for (int i = 0; i < 8; ++i) {
        int e = c0 + i * 512 + tid;
        myb[i] = -1;
        if (e < E) {
            int r = rows[e];
            int b = r / BS;
            int rr = r - b * BS;
            myb[i] = b;
            mypack[i] = (cols[e] << 8) | rr;
            myval[i] = vals[e];
            atomicAdd(&hist[b], 1);
        }
    }
    __syncthreads();

    int h = hist[tid];
    if (h) posBase[tid] = atomicAdd(&bcur[tid], h);
    hist[tid] = 0;   // reuse as local cursor
    __syncthreads();

    #pragma unroll
    for (int i = 0; i < 8; ++i) {
        if (myb[i] >= 0) {
            int p = posBase[myb[i]] + atomicAdd(&hist[myb[i]], 1);
            int2 cv; cv.x = mypack[i]; cv.y = __float_as_int(myval[i]);
            seg[p] = cv;
        }
    }
}

// ---------------- SpMM by bucket: LDS accumulators, 8-deep gather batch ------
__global__ __launch_bounds__(1024) void spmm_bucket_kernel(
    const int* __restrict__ bbase, const int2* __restrict__ seg,
    const float* __restrict__ x, float* __restrict__ y,
    const float* __restrict__ bias, int N)
{
    __shared__ float ylds[BS * OUT_CH];   // 24.5 KB

    const int tid = threadIdx.x;
    const int b = blockIdx.x;
    for (int i = tid; i < BS * OUT_CH; i += 1024) ylds[i] = 0.f;
    __syncthreads();

    const int s = bbase[b];
    const int e = bbase[b + 1];
    const int lane = tid & 63;
    const int wv = tid >> 6;   // 16 waves

    // each wave: runs of 8 consecutive edges, strided by 16 waves * 8
    for (int i0 = s + wv * 8; i0 < e; i0 += 16 * 8) {
        if (i0 + 8 <= e) {
            int2 c0 = seg[i0    ], c1 = seg[i0 + 1];
            int2 c2 = seg[i0 + 2], c3 = seg[i0 + 3];
            int2 c4 = seg[i0 + 4], c5 = seg[i0 + 5];
            int2 c6 = seg[i0 + 6], c7 = seg[i0 + 7];
            float x0 = x[(size_t)(((unsigned)c0.x) >> 8) * OUT_CH + lane];
            float x1 = x[(size_t)(((unsigned)c1.x) >> 8) * OUT_CH + lane];
            float x2 = x[(size_t)(((unsigned)c2.x) >> 8) * OUT_CH + lane];
            float x3 = x[(size_t)(((unsigned)c3.x) >> 8) * OUT_CH + lane];
            float x4 = x[(size_t)(((unsigned)c4.x) >> 8) * OUT_CH + lane];
            float x5 = x[(size_t)(((unsigned)c5.x) >> 8) * OUT_CH + lane];
            float x6 = x[(size_t)(((unsigned)c6.x) >> 8) * OUT_CH + lane];
            float x7 = x[(size_t)(((unsigned)c7.x) >> 8) * OUT_CH + lane];
            atomicAdd(&ylds[(c0.x & 255) * OUT_CH + lane], __int_as_float(c0.y) * x0);
            atomicAdd(&ylds[(c1.x & 255) * OUT_CH + lane], __int_as_float(c1.y) * x1);
            atomicAdd(&ylds[(c2.x & 255) * OUT_CH + lane], __int_as_float(c2.y) * x2);
            atomicAdd(&ylds[(c3.x & 255) * OUT_CH + lane], __int_as_float(c3.y) * x3);
            atomicAdd(&ylds[(c4.x & 255) * OUT_CH + lane], __int_as_float(c4.y) * x4);
            atomicAdd(&ylds[(c5.x & 255) * OUT_CH + lane], __int_as_float(c5.y) * x5);
            atomicAdd(&ylds[(c6.x & 255) * OUT_CH + lane], __int_as_float(c6.y) * x6);
            atomicAdd(&ylds[(c7.x & 255) * OUT_CH + lane], __int_as_float(c7.y) * x7);
        } else {
            for (int i = i0; i < e; ++i) {
                int2 c = seg[i];
                float xv = x[(size_t)(((unsigned)c.x) >> 8) * OUT_CH + lane];
                atomicAdd(&ylds[(c.x & 255) * OUT_CH + lane], __int_as_float(c.y) * xv);
            }
        }
    }
    __syncthreads();

    const int rowBase = b * BS;
    for (int idx = tid; idx < BS * OUT_CH; idx += 1024) {
        int r = rowBase + (idx >> 6);
        if (r < N) {
            float o = ylds[idx];
            if (bias) o += bias[idx & 63];
            y[(size_t)r * OUT_CH + (idx & 63)] = o;
        }
    }
}

// ---------------- launch -----------------------------------------------------
static inline size_t align_up(size_t v) { return (v + 255) & ~(size_t)255; }

extern "C" void kernel_launch(void* const* d_in, const int* in_sizes, int n_in,
                              void* d_out, int out_size, void* d_ws, size_t ws_size,
                              hipStream_t stream)
{
    const int*   adj  = (const int*)d_in[0];    // [2,E]
    const float* vals = (const float*)d_in[1];  // [E]
    const float* feat = (const float*)d_in[2];  // [N,512]
    const float* Wm   = (const float*)d_in[3];  // [512,64]
    const float* bias = (const float*)d_in[4];  // [64]

    const int E = in_sizes[1];
    const int N = in_sizes[2] / IN_CH;
    const int* rows  = adj;
    const int* colsI = adj + E;

    char* w = (char*)d_ws;
    size_t o = 0;
    float* B0    = (float*)(w + o); o += align_up((size_t)N * OUT_CH * sizeof(float));
    float* Y1    = (float*)(w + o); o += align_up((size_t)N * OUT_CH * sizeof(float));
    int*   bcnt  = (int*)  (w + o); o += align_up(NB * sizeof(int));
    int*   bbase = (int*)  (w + o); o += align_up((NB + 1) * sizeof(int));
    int*   bcur  = (int*)  (w + o); o += align_up(NB * sizeof(int));
    int2*  seg   = (int2*) (w + o); o += align_up((size_t)E * sizeof(int2));
    (void)ws_size; (void)n_in; (void)out_size;

    // 1. dense projection -> B0
    gemm_kernel<<<(N + 63) / 64, 256, 0, stream>>>(feat, Wm, B0, N);

    // 2. bucket the edges (no per-row CSR)
    hipMemsetAsync(bcnt, 0, NB * sizeof(int), stream);
    count_kernel<<<1024, 512, 0, stream>>>(rows, bcnt, E);
    scan_kernel<<<1, NB, 0, stream>>>(bcnt, bbase, bcur);
    bucket_scatter_kernel<<<(E + CHUNK - 1) / CHUNK, 512, 0, stream>>>(
        rows, colsI, vals, bcur, seg, E);

    // 3. two propagation rounds (bias fused into the last)
    spmm_bucket_kernel<<<NB, 1024, 0, stream>>>(bbase, seg, B0, Y1, nullptr, N);
    spmm_bucket_kernel<<<NB, 1024, 0, stream>>>(bbase, seg, Y1, (float*)d_out, bias, N);
}

// Round 4
// 185.369 us; speedup vs baseline: 6.2895x; 6.1567x over previous
//
#include <hip/hip_runtime.h>
#include <hip/hip_bf16.h>

typedef __attribute__((ext_vector_type(8))) __bf16 bf16x8;
typedef __attribute__((ext_vector_type(4))) float f32x4;

#define IN_CH 512
#define OUT_CH 64
#define WT_STRIDE 520   // 512 + 8 bf16 pad
#define BS 98           // rows per bucket (rowres fits in 8 bits)
#define NB 512          // buckets; BS*NB = 50176 >= N
#define CHUNK 4096      // edges per scatter block (512 thr x 8)
#define CAP 4608        // max edges per bucket handled by sort (9*512; mean 3125)

// ---------------- GEMM: base = features @ W (bf16 MFMA, fp32 accum) ----------
__global__ __launch_bounds__(256) void gemm_kernel(
    const float* __restrict__ A, const float* __restrict__ W,
    float* __restrict__ out, int N)
{
    __shared__ __align__(16) __bf16 Wt[OUT_CH * WT_STRIDE];

    const int tid = threadIdx.x;
    for (int idx = tid; idx < IN_CH * OUT_CH; idx += 256) {
        int k = idx >> 6, n = idx & 63;
        Wt[n * WT_STRIDE + k] = (__bf16)W[idx];
    }
    __syncthreads();

    const int lane = tid & 63;
    const int wave = tid >> 6;
    const int row0 = blockIdx.x * 64 + wave * 16;
    int row_a = row0 + (lane & 15);
    int row_c = row_a < N ? row_a : N - 1;

    const float* arow = A + (size_t)row_c * IN_CH;
    const int kg = (lane >> 4) * 8;
    const int col = lane & 15;

    f32x4 acc0 = {0.f,0.f,0.f,0.f}, acc1 = {0.f,0.f,0.f,0.f};
    f32x4 acc2 = {0.f,0.f,0.f,0.f}, acc3 = {0.f,0.f,0.f,0.f};

    for (int ks = 0; ks < IN_CH / 32; ++ks) {
        int kb = ks * 32 + kg;
        float4 p = *(const float4*)(arow + kb);
        float4 q = *(const float4*)(arow + kb + 4);
        bf16x8 a;
        a[0]=(__bf16)p.x; a[1]=(__bf16)p.y; a[2]=(__bf16)p.z; a[3]=(__bf16)p.w;
        a[4]=(__bf16)q.x; a[5]=(__bf16)q.y; a[6]=(__bf16)q.z; a[7]=(__bf16)q.w;
        bf16x8 b0 = *(const bf16x8*)(&Wt[(col     ) * WT_STRIDE + kb]);
        bf16x8 b1 = *(const bf16x8*)(&Wt[(col + 16) * WT_STRIDE + kb]);
        bf16x8 b2 = *(const bf16x8*)(&Wt[(col + 32) * WT_STRIDE + kb]);
        bf16x8 b3 = *(const bf16x8*)(&Wt[(col + 48) * WT_STRIDE + kb]);
        acc0 = __builtin_amdgcn_mfma_f32_16x16x32_bf16(a, b0, acc0, 0, 0, 0);
        acc1 = __builtin_amdgcn_mfma_f32_16x16x32_bf16(a, b1, acc1, 0, 0, 0);
        acc2 = __builtin_amdgcn_mfma_f32_16x16x32_bf16(a, b2, acc2, 0, 0, 0);
        acc3 = __builtin_amdgcn_mfma_f32_16x16x32_bf16(a, b3, acc3, 0, 0, 0);
    }

    int rr = row0 + (lane >> 4) * 4;
    for (int i = 0; i < 4; ++i) {
        int r = rr + i;
        if (r < N) {
            float* o = out + (size_t)r * OUT_CH;
            o[col]      = acc0[i];
            o[col + 16] = acc1[i];
            o[col + 32] = acc2[i];
            o[col + 48] = acc3[i];
        }
    }
}

// ---------------- bucket count ----------------------------------------------
__global__ __launch_bounds__(512) void count_kernel(
    const int* __restrict__ rows, int* __restrict__ bcnt, int E)
{
    __shared__ int hist[NB];
    const int tid = threadIdx.x;
    hist[tid] = 0;
    __syncthreads();
    for (int e = blockIdx.x * blockDim.x + tid; e < E; e += gridDim.x * blockDim.x) {
        int b = rows[e] / BS;
        atomicAdd(&hist[b], 1);
    }
    __syncthreads();
    if (hist[tid]) atomicAdd(&bcnt[tid], hist[tid]);
}

// ---------------- NB-wide exclusive scan -------------------------------------
__global__ __launch_bounds__(NB) void scan_kernel(
    const int* __restrict__ bcnt, int* __restrict__ bbase, int* __restrict__ bcur)
{
    __shared__ int lds[NB];
    const int t = threadIdx.x;
    int v = bcnt[t];
    lds[t] = v;
    __syncthreads();
    for (int ofs = 1; ofs < NB; ofs <<= 1) {
        int u = 0;
        if (t >= ofs) u = lds[t - ofs];
        __syncthreads();
        if (t >= ofs) lds[t] += u;
        __syncthreads();
    }
    int excl = lds[t] - v;
    bbase[t] = excl;
    bcur[t]  = excl;
    if (t == NB - 1) bbase[NB] = lds[NB - 1];
}

// ---------------- bucket scatter: group 4096 edges per block -----------------
__global__ __launch_bounds__(512) void bucket_scatter_kernel(
    const int* __restrict__ rows, const int* __restrict__ cols,
    const float* __restrict__ vals, int* __restrict__ bcur,
    int2* __restrict__ seg, int E)
{
    __shared__ int hist[NB];
    __shared__ int posBase[NB];
    const int tid = threadIdx.x;
    const int c0 = blockIdx.x * CHUNK;

    hist[tid] = 0;
    __syncthreads();

    int myb[8], mypack[8]; float myval[8];
    #pragma unroll
    for (int i = 0; i < 8; ++i) {
        int e = c0 + i * 512 + tid;
        myb[i] = -1;
        if (e < E) {
            int r = rows[e];
            int b = r / BS;
            int rr = r - b * BS;
            myb[i] = b;
            mypack[i] = (cols[e] << 8) | rr;
            myval[i] = vals[e];
            atomicAdd(&hist[b], 1);
        }
    }
    __syncthreads();

    int h = hist[tid];
    if (h) posBase[tid] = atomicAdd(&bcur[tid], h);
    hist[tid] = 0;   // reuse as local cursor
    __syncthreads();

    #pragma unroll
    for (int i = 0; i < 8; ++i) {
        if (myb[i] >= 0) {
            int p = posBase[myb[i]] + atomicAdd(&hist[myb[i]], 1);
            int2 cv; cv.x = mypack[i]; cv.y = __float_as_int(myval[i]);
            seg[p] = cv;
        }
    }
}

// ---------------- per-bucket LDS sort -> full CSR (in-place) -----------------
// Packs become {col, val} after this kernel; offs[] gets per-row bases.
__global__ __launch_bounds__(512) void sort_kernel(
    const int* __restrict__ bbase, int2* __restrict__ seg,
    int* __restrict__ offs)
{
    __shared__ int2 sorted[CAP];           // 36.8 KB
    __shared__ int hist[BS + 1];
    __shared__ int cursor[BS];

    const int b = blockIdx.x;
    const int t = threadIdx.x;
    const int s = bbase[b];
    const int cnt = bbase[b + 1] - s;

    if (t < BS + 1) hist[t] = 0;
    __syncthreads();

    int2 ed[9];
    #pragma unroll
    for (int j = 0; j < 9; ++j) {
        int idx = t + j * 512;
        if (idx < cnt) {
            ed[j] = seg[s + idx];
            atomicAdd(&hist[ed[j].x & 255], 1);
        }
    }
    __syncthreads();

    if (t == 0) {
        int run = 0;
        for (int i = 0; i < BS; ++i) { int c = hist[i]; hist[i] = run; run += c; }
        hist[BS] = run;
    }
    __syncthreads();

    if (t < BS) {
        cursor[t] = hist[t];
        offs[b * BS + t] = s + hist[t];
    }
    __syncthreads();

    #pragma unroll
    for (int j = 0; j < 9; ++j) {
        int idx = t + j * 512;
        if (idx < cnt) {
            int pos = atomicAdd(&cursor[ed[j].x & 255], 1);
            int2 cv;
            cv.x = (int)(((unsigned)ed[j].x) >> 8);   // col
            cv.y = ed[j].y;                            // val bits
            sorted[pos] = cv;
        }
    }
    __syncthreads();

    #pragma unroll
    for (int j = 0; j < 9; ++j) {
        int idx = t + j * 512;
        if (idx < cnt) seg[s + idx] = sorted[idx];
    }
}

// ---------------- SpMM: one wave per row, register accumulation, 8-deep ------
__global__ __launch_bounds__(256) void spmm_row_kernel(
    const int* __restrict__ offs, const int2* __restrict__ seg,
    const float* __restrict__ x, float* __restrict__ y,
    const float* __restrict__ bias, int N)
{
    const int lane = threadIdx.x & 63;
    int r = blockIdx.x * 4 + (threadIdx.x >> 6);
    if (r >= N) return;
    r = __builtin_amdgcn_readfirstlane(r);

    const int s = offs[r];
    const int e = offs[r + 1];
    const float* xl = x + lane;

    float acc = 0.f;
    int i0 = s;
    for (; i0 + 8 <= e; i0 += 8) {
        int2 c0 = seg[i0    ], c1 = seg[i0 + 1];
        int2 c2 = seg[i0 + 2], c3 = seg[i0 + 3];
        int2 c4 = seg[i0 + 4], c5 = seg[i0 + 5];
        int2 c6 = seg[i0 + 6], c7 = seg[i0 + 7];
        float x0 = xl[(size_t)c0.x * OUT_CH];
        float x1 = xl[(size_t)c1.x * OUT_CH];
        float x2 = xl[(size_t)c2.x * OUT_CH];
        float x3 = xl[(size_t)c3.x * OUT_CH];
        float x4 = xl[(size_t)c4.x * OUT_CH];
        float x5 = xl[(size_t)c5.x * OUT_CH];
        float x6 = xl[(size_t)c6.x * OUT_CH];
        float x7 = xl[(size_t)c7.x * OUT_CH];
        acc = fmaf(__int_as_float(c0.y), x0, acc);
        acc = fmaf(__int_as_float(c1.y), x1, acc);
        acc = fmaf(__int_as_float(c2.y), x2, acc);
        acc = fmaf(__int_as_float(c3.y), x3, acc);
        acc = fmaf(__int_as_float(c4.y), x4, acc);
        acc = fmaf(__int_as_float(c5.y), x5, acc);
        acc = fmaf(__int_as_float(c6.y), x6, acc);
        acc = fmaf(__int_as_float(c7.y), x7, acc);
    }
    if (i0 < e) {
        // clamped batch of up to 8 with zeroed weights (keeps loads independent)
        #pragma unroll
        for (int j = 0; j < 8; ++j) {
            int ij = i0 + j < e ? i0 + j : e - 1;
            int2 c = seg[ij];
            float w = (i0 + j < e) ? __int_as_float(c.y) : 0.f;
            float xv = xl[(size_t)c.x * OUT_CH];
            acc = fmaf(w, xv, acc);
        }
    }
    if (bias) acc += bias[lane];
    y[(size_t)r * OUT_CH + lane] = acc;
}

// ---------------- launch -----------------------------------------------------
static inline size_t align_up(size_t v) { return (v + 255) & ~(size_t)255; }

extern "C" void kernel_launch(void* const* d_in, const int* in_sizes, int n_in,
                              void* d_out, int out_size, void* d_ws, size_t ws_size,
                              hipStream_t stream)
{
    const int*   adj  = (const int*)d_in[0];    // [2,E]
    const float* vals = (const float*)d_in[1];  // [E]
    const float* feat = (const float*)d_in[2];  // [N,512]
    const float* Wm   = (const float*)d_in[3];  // [512,64]
    const float* bias = (const float*)d_in[4];  // [64]

    const int E = in_sizes[1];
    const int N = in_sizes[2] / IN_CH;
    const int* rows  = adj;
    const int* colsI = adj + E;

    char* w = (char*)d_ws;
    size_t o = 0;
    float* B0    = (float*)(w + o); o += align_up((size_t)N * OUT_CH * sizeof(float));
    float* Y1    = (float*)(w + o); o += align_up((size_t)N * OUT_CH * sizeof(float));
    int*   bcnt  = (int*)  (w + o); o += align_up(NB * sizeof(int));
    int*   bbase = (int*)  (w + o); o += align_up((NB + 1) * sizeof(int));
    int*   bcur  = (int*)  (w + o); o += align_up(NB * sizeof(int));
    int*   offs  = (int*)  (w + o); o += align_up((size_t)(NB * BS + 1) * sizeof(int));
    int2*  seg   = (int2*) (w + o); o += align_up((size_t)E * sizeof(int2));
    (void)ws_size; (void)n_in; (void)out_size;

    // 1. dense projection -> B0
    gemm_kernel<<<(N + 63) / 64, 256, 0, stream>>>(feat, Wm, B0, N);

    // 2. CSR build: bucket + per-bucket LDS sort
    hipMemsetAsync(bcnt, 0, NB * sizeof(int), stream);
    count_kernel<<<1024, 512, 0, stream>>>(rows, bcnt, E);
    scan_kernel<<<1, NB, 0, stream>>>(bcnt, bbase, bcur);
    bucket_scatter_kernel<<<(E + CHUNK - 1) / CHUNK, 512, 0, stream>>>(
        rows, colsI, vals, bcur, seg, E);
    sort_kernel<<<NB, 512, 0, stream>>>(bbase, seg, offs);

    // 3. two propagation rounds (bias fused into the last)
    spmm_row_kernel<<<(N + 3) / 4, 256, 0, stream>>>(offs, seg, B0, Y1, nullptr, N);
    spmm_row_kernel<<<(N + 3) / 4, 256, 0, stream>>>(offs, seg, Y1, (float*)d_out, bias, N);
}

// Round 5
// 158.133 us; speedup vs baseline: 7.3728x; 1.1722x over previous
//
#include <hip/hip_runtime.h>
#include <hip/hip_bf16.h>

typedef __attribute__((ext_vector_type(8))) __bf16 bf16x8;
typedef __attribute__((ext_vector_type(4))) float f32x4;

#define IN_CH 512
#define OUT_CH 64
#define WT_STRIDE 520   // 512 + 8 bf16 pad
#define BS 98           // rows per bucket (rowres fits in 8 bits)
#define NB 512          // buckets; BS*NB = 50176 >= N
#define CHUNK 4096      // edges per scatter block (512 thr x 8)
#define CAP 4096        // fixed slots per bucket (mean 3125, +17 sigma)

// ---------------- GEMM: base = features @ W (bf16 MFMA, fp32 accum) ----------
// Block 0 also initializes the bucket cursors (stream-ordered before scatter).
__global__ __launch_bounds__(256) void gemm_kernel(
    const float* __restrict__ A, const float* __restrict__ W,
    float* __restrict__ out, int* __restrict__ bcur, int N)
{
    __shared__ __align__(16) __bf16 Wt[OUT_CH * WT_STRIDE];

    const int tid = threadIdx.x;
    if (blockIdx.x == 0) {
        for (int i = tid; i < NB; i += 256) bcur[i] = i * CAP;
    }
    for (int idx = tid; idx < IN_CH * OUT_CH; idx += 256) {
        int k = idx >> 6, n = idx & 63;
        Wt[n * WT_STRIDE + k] = (__bf16)W[idx];
    }
    __syncthreads();

    const int lane = tid & 63;
    const int wave = tid >> 6;
    const int row0 = blockIdx.x * 64 + wave * 16;
    int row_a = row0 + (lane & 15);
    int row_c = row_a < N ? row_a : N - 1;

    const float* arow = A + (size_t)row_c * IN_CH;
    const int kg = (lane >> 4) * 8;
    const int col = lane & 15;

    f32x4 acc0 = {0.f,0.f,0.f,0.f}, acc1 = {0.f,0.f,0.f,0.f};
    f32x4 acc2 = {0.f,0.f,0.f,0.f}, acc3 = {0.f,0.f,0.f,0.f};

    for (int ks = 0; ks < IN_CH / 32; ++ks) {
        int kb = ks * 32 + kg;
        float4 p = *(const float4*)(arow + kb);
        float4 q = *(const float4*)(arow + kb + 4);
        bf16x8 a;
        a[0]=(__bf16)p.x; a[1]=(__bf16)p.y; a[2]=(__bf16)p.z; a[3]=(__bf16)p.w;
        a[4]=(__bf16)q.x; a[5]=(__bf16)q.y; a[6]=(__bf16)q.z; a[7]=(__bf16)q.w;
        bf16x8 b0 = *(const bf16x8*)(&Wt[(col     ) * WT_STRIDE + kb]);
        bf16x8 b1 = *(const bf16x8*)(&Wt[(col + 16) * WT_STRIDE + kb]);
        bf16x8 b2 = *(const bf16x8*)(&Wt[(col + 32) * WT_STRIDE + kb]);
        bf16x8 b3 = *(const bf16x8*)(&Wt[(col + 48) * WT_STRIDE + kb]);
        acc0 = __builtin_amdgcn_mfma_f32_16x16x32_bf16(a, b0, acc0, 0, 0, 0);
        acc1 = __builtin_amdgcn_mfma_f32_16x16x32_bf16(a, b1, acc1, 0, 0, 0);
        acc2 = __builtin_amdgcn_mfma_f32_16x16x32_bf16(a, b2, acc2, 0, 0, 0);
        acc3 = __builtin_amdgcn_mfma_f32_16x16x32_bf16(a, b3, acc3, 0, 0, 0);
    }

    int rr = row0 + (lane >> 4) * 4;
    for (int i = 0; i < 4; ++i) {
        int r = rr + i;
        if (r < N) {
            float* o = out + (size_t)r * OUT_CH;
            o[col]      = acc0[i];
            o[col + 16] = acc1[i];
            o[col + 32] = acc2[i];
            o[col + 48] = acc3[i];
        }
    }
}

// ---------------- bucket scatter: group 4096 edges per block -----------------
__global__ __launch_bounds__(512) void bucket_scatter_kernel(
    const int* __restrict__ rows, const int* __restrict__ cols,
    const float* __restrict__ vals, int* __restrict__ bcur,
    int2* __restrict__ seg, int E)
{
    __shared__ int hist[NB];
    __shared__ int posBase[NB];
    const int tid = threadIdx.x;
    const int c0 = blockIdx.x * CHUNK;

    hist[tid] = 0;
    __syncthreads();

    int myb[8], mypack[8]; float myval[8];
    #pragma unroll
    for (int i = 0; i < 8; ++i) {
        int e = c0 + i * 512 + tid;
        myb[i] = -1;
        if (e < E) {
            int r = rows[e];
            int b = r / BS;
            int rr = r - b * BS;
            myb[i] = b;
            mypack[i] = (cols[e] << 8) | rr;
            myval[i] = vals[e];
            atomicAdd(&hist[b], 1);
        }
    }
    __syncthreads();

    int h = hist[tid];
    if (h) posBase[tid] = atomicAdd(&bcur[tid], h);
    hist[tid] = 0;   // reuse as local cursor
    __syncthreads();

    #pragma unroll
    for (int i = 0; i < 8; ++i) {
        if (myb[i] >= 0) {
            int p = posBase[myb[i]] + atomicAdd(&hist[myb[i]], 1);
            int2 cv; cv.x = mypack[i]; cv.y = __float_as_int(myval[i]);
            seg[p] = cv;
        }
    }
}

// ---------------- per-bucket LDS sort -> per-row offs/rend (in-place) --------
__global__ __launch_bounds__(512) void sort_kernel(
    const int* __restrict__ bcur, int2* __restrict__ seg,
    int* __restrict__ offs, int* __restrict__ rend)
{
    __shared__ int2 sorted[CAP];           // 32 KB
    __shared__ int hist[BS + 1];
    __shared__ int cursor[BS];

    const int b = blockIdx.x;
    const int t = threadIdx.x;
    const int s = b * CAP;
    const int cnt = bcur[b] - s;

    if (t < BS + 1) hist[t] = 0;
    __syncthreads();

    int2 ed[8];
    #pragma unroll
    for (int j = 0; j < 8; ++j) {
        int idx = t + j * 512;
        if (idx < cnt) {
            ed[j] = seg[s + idx];
            atomicAdd(&hist[ed[j].x & 255], 1);
        }
    }
    __syncthreads();

    if (t == 0) {
        int run = 0;
        for (int i = 0; i < BS; ++i) { int c = hist[i]; hist[i] = run; run += c; }
        hist[BS] = run;
    }
    __syncthreads();

    if (t < BS) {
        cursor[t] = hist[t];
        offs[b * BS + t] = s + hist[t];
        rend[b * BS + t] = s + hist[t + 1];
    }
    __syncthreads();

    #pragma unroll
    for (int j = 0; j < 8; ++j) {
        int idx = t + j * 512;
        if (idx < cnt) {
            int pos = atomicAdd(&cursor[ed[j].x & 255], 1);
            int2 cv;
            cv.x = (int)(((unsigned)ed[j].x) >> 8);   // col
            cv.y = ed[j].y;                            // val bits
            sorted[pos] = cv;
        }
    }
    __syncthreads();

    #pragma unroll
    for (int j = 0; j < 8; ++j) {
        int idx = t + j * 512;
        if (idx < cnt) seg[s + idx] = sorted[idx];
    }
}

// ---------------- SpMM: one wave per row, register accumulation, 8-deep ------
__global__ __launch_bounds__(256) void spmm_row_kernel(
    const int* __restrict__ offs, const int* __restrict__ rend,
    const int2* __restrict__ seg,
    const float* __restrict__ x, float* __restrict__ y,
    const float* __restrict__ bias, int N)
{
    const int lane = threadIdx.x & 63;
    int r = blockIdx.x * 4 + (threadIdx.x >> 6);
    if (r >= N) return;
    r = __builtin_amdgcn_readfirstlane(r);

    const int s = offs[r];
    const int e = rend[r];
    const float* xl = x + lane;

    float acc = 0.f;
    int i0 = s;
    for (; i0 + 8 <= e; i0 += 8) {
        int2 c0 = seg[i0    ], c1 = seg[i0 + 1];
        int2 c2 = seg[i0 + 2], c3 = seg[i0 + 3];
        int2 c4 = seg[i0 + 4], c5 = seg[i0 + 5];
        int2 c6 = seg[i0 + 6], c7 = seg[i0 + 7];
        float x0 = xl[(size_t)c0.x * OUT_CH];
        float x1 = xl[(size_t)c1.x * OUT_CH];
        float x2 = xl[(size_t)c2.x * OUT_CH];
        float x3 = xl[(size_t)c3.x * OUT_CH];
        float x4 = xl[(size_t)c4.x * OUT_CH];
        float x5 = xl[(size_t)c5.x * OUT_CH];
        float x6 = xl[(size_t)c6.x * OUT_CH];
        float x7 = xl[(size_t)c7.x * OUT_CH];
        acc = fmaf(__int_as_float(c0.y), x0, acc);
        acc = fmaf(__int_as_float(c1.y), x1, acc);
        acc = fmaf(__int_as_float(c2.y), x2, acc);
        acc = fmaf(__int_as_float(c3.y), x3, acc);
        acc = fmaf(__int_as_float(c4.y), x4, acc);
        acc = fmaf(__int_as_float(c5.y), x5, acc);
        acc = fmaf(__int_as_float(c6.y), x6, acc);
        acc = fmaf(__int_as_float(c7.y), x7, acc);
    }
    if (i0 < e) {
        #pragma unroll
        for (int j = 0; j < 8; ++j) {
            int ij = i0 + j < e ? i0 + j : e - 1;
            int2 c = seg[ij];
            float w = (i0 + j < e) ? __int_as_float(c.y) : 0.f;
            float xv = xl[(size_t)c.x * OUT_CH];
            acc = fmaf(w, xv, acc);
        }
    }
    if (bias) acc += bias[lane];
    y[(size_t)r * OUT_CH + lane] = acc;
}

// ---------------- launch -----------------------------------------------------
static inline size_t align_up(size_t v) { return (v + 255) & ~(size_t)255; }

extern "C" void kernel_launch(void* const* d_in, const int* in_sizes, int n_in,
                              void* d_out, int out_size, void* d_ws, size_t ws_size,
                              hipStream_t stream)
{
    const int*   adj  = (const int*)d_in[0];    // [2,E]
    const float* vals = (const float*)d_in[1];  // [E]
    const float* feat = (const float*)d_in[2];  // [N,512]
    const float* Wm   = (const float*)d_in[3];  // [512,64]
    const float* bias = (const float*)d_in[4];  // [64]

    const int E = in_sizes[1];
    const int N = in_sizes[2] / IN_CH;
    const int* rows  = adj;
    const int* colsI = adj + E;

    char* w = (char*)d_ws;
    size_t o = 0;
    float* B0   = (float*)(w + o); o += align_up((size_t)N * OUT_CH * sizeof(float));
    int*   bcur = (int*)  (w + o); o += align_up(NB * sizeof(int));
    int*   offs = (int*)  (w + o); o += align_up((size_t)NB * BS * sizeof(int));
    int*   rend = (int*)  (w + o); o += align_up((size_t)NB * BS * sizeof(int));
    int2*  seg  = (int2*) (w + o); o += align_up((size_t)NB * CAP * sizeof(int2));
    (void)ws_size; (void)n_in; (void)out_size;

    float* out = (float*)d_out;

    // 1. dense projection -> d_out (+ bcur init in block 0)
    gemm_kernel<<<(N + 63) / 64, 256, 0, stream>>>(feat, Wm, out, bcur, N);

    // 2. CSR build: fixed-capacity bucket scatter + per-bucket LDS sort
    bucket_scatter_kernel<<<(E + CHUNK - 1) / CHUNK, 512, 0, stream>>>(
        rows, colsI, vals, bcur, seg, E);
    sort_kernel<<<NB, 512, 0, stream>>>(bcur, seg, offs, rend);

    // 3. two propagation rounds (bias fused into the last)
    spmm_row_kernel<<<(N + 3) / 4, 256, 0, stream>>>(offs, rend, seg, out, B0, nullptr, N);
    spmm_row_kernel<<<(N + 3) / 4, 256, 0, stream>>>(offs, rend, seg, B0, out, bias, N);
}

// Round 6
// 157.479 us; speedup vs baseline: 7.4034x; 1.0042x over previous
//
#include <hip/hip_runtime.h>
#include <hip/hip_bf16.h>

typedef __attribute__((ext_vector_type(8))) __bf16 bf16x8;
typedef __attribute__((ext_vector_type(4))) float f32x4;

#define IN_CH 512
#define OUT_CH 64
#define BS 98           // rows per bucket (rowres fits in 8 bits)
#define NB 512          // buckets; BS*NB = 50176 >= N
#define CHUNK 4096      // edges per scatter block (512 thr x 8)
#define CAP 4096        // fixed slots per bucket (mean 3125, +17 sigma)

// ---------------- prep: W -> MFMA B-fragments (bf16) + bcur init -------------
// Wf layout: frag (ct,ks) at [(ct*16+ks)*64 + lane]*8 .. +7  (bf16 elements)
// lane l of frag (ct,ks) holds W[k = ks*32 + (l>>4)*8 + j][n = ct*16 + (l&15)]
__global__ __launch_bounds__(512) void prep_kernel(
    const float* __restrict__ W, __hip_bfloat16* __restrict__ Wf,
    int* __restrict__ bcur)
{
    const int t = blockIdx.x * 512 + threadIdx.x;   // 0..4095
    if (t < NB) bcur[t] = t * CAP;
    const int ct = t >> 10;          // 0..3
    const int rem = t & 1023;
    const int ks = rem >> 6;         // 0..15
    const int l = rem & 63;          // lane
    const int col = ct * 16 + (l & 15);
    const int kb = ks * 32 + (l >> 4) * 8;
    __hip_bfloat16* dst = Wf + (size_t)t * 8;
    #pragma unroll
    for (int j = 0; j < 8; ++j)
        dst[j] = (__hip_bfloat16)W[(size_t)(kb + j) * OUT_CH + col];
}

// ---------------- GEMM: base = features @ W (bf16 MFMA, no LDS) --------------
__global__ __launch_bounds__(256) void gemm_kernel(
    const float* __restrict__ A, const __hip_bfloat16* __restrict__ Wf,
    float* __restrict__ out, int N)
{
    const int tid = threadIdx.x;
    const int lane = tid & 63;
    const int wave = tid >> 6;
    const int row0 = blockIdx.x * 64 + wave * 16;
    int row_a = row0 + (lane & 15);
    int row_c = row_a < N ? row_a : N - 1;

    const float* arow = A + (size_t)row_c * IN_CH;
    const int kg = (lane >> 4) * 8;
    const int col = lane & 15;
    const bf16x8* wf = (const bf16x8*)Wf;

    f32x4 acc0 = {0.f,0.f,0.f,0.f}, acc1 = {0.f,0.f,0.f,0.f};
    f32x4 acc2 = {0.f,0.f,0.f,0.f}, acc3 = {0.f,0.f,0.f,0.f};

    #pragma unroll 4
    for (int ks = 0; ks < IN_CH / 32; ++ks) {
        int kb = ks * 32 + kg;
        float4 p = *(const float4*)(arow + kb);
        float4 q = *(const float4*)(arow + kb + 4);
        bf16x8 b0 = wf[(0 * 16 + ks) * 64 + lane];
        bf16x8 b1 = wf[(1 * 16 + ks) * 64 + lane];
        bf16x8 b2 = wf[(2 * 16 + ks) * 64 + lane];
        bf16x8 b3 = wf[(3 * 16 + ks) * 64 + lane];
        bf16x8 a;
        a[0]=(__bf16)p.x; a[1]=(__bf16)p.y; a[2]=(__bf16)p.z; a[3]=(__bf16)p.w;
        a[4]=(__bf16)q.x; a[5]=(__bf16)q.y; a[6]=(__bf16)q.z; a[7]=(__bf16)q.w;
        acc0 = __builtin_amdgcn_mfma_f32_16x16x32_bf16(a, b0, acc0, 0, 0, 0);
        acc1 = __builtin_amdgcn_mfma_f32_16x16x32_bf16(a, b1, acc1, 0, 0, 0);
        acc2 = __builtin_amdgcn_mfma_f32_16x16x32_bf16(a, b2, acc2, 0, 0, 0);
        acc3 = __builtin_amdgcn_mfma_f32_16x16x32_bf16(a, b3, acc3, 0, 0, 0);
    }

    int rr = row0 + (lane >> 4) * 4;
    for (int i = 0; i < 4; ++i) {
        int r = rr + i;
        if (r < N) {
            float* o = out + (size_t)r * OUT_CH;
            o[col]      = acc0[i];
            o[col + 16] = acc1[i];
            o[col + 32] = acc2[i];
            o[col + 48] = acc3[i];
        }
    }
}

// ---------------- bucket scatter: group 4096 edges per block -----------------
__global__ __launch_bounds__(512) void bucket_scatter_kernel(
    const int* __restrict__ rows, const int* __restrict__ cols,
    const float* __restrict__ vals, int* __restrict__ bcur,
    int2* __restrict__ seg, int E)
{
    __shared__ int hist[NB];
    __shared__ int posBase[NB];
    const int tid = threadIdx.x;
    const int c0 = blockIdx.x * CHUNK;

    hist[tid] = 0;
    __syncthreads();

    int myb[8], mypack[8]; float myval[8];
    #pragma unroll
    for (int i = 0; i < 8; ++i) {
        int e = c0 + i * 512 + tid;
        myb[i] = -1;
        if (e < E) {
            int r = rows[e];
            int b = r / BS;
            int rr = r - b * BS;
            myb[i] = b;
            mypack[i] = (cols[e] << 8) | rr;
            myval[i] = vals[e];
            atomicAdd(&hist[b], 1);
        }
    }
    __syncthreads();

    int h = hist[tid];
    if (h) posBase[tid] = atomicAdd(&bcur[tid], h);
    hist[tid] = 0;   // reuse as local cursor
    __syncthreads();

    #pragma unroll
    for (int i = 0; i < 8; ++i) {
        if (myb[i] >= 0) {
            int p = posBase[myb[i]] + atomicAdd(&hist[myb[i]], 1);
            int2 cv; cv.x = mypack[i]; cv.y = __float_as_int(myval[i]);
            seg[p] = cv;
        }
    }
}

// ---------------- per-bucket LDS sort -> per-row offs/rend (in-place) --------
__global__ __launch_bounds__(512) void sort_kernel(
    const int* __restrict__ bcur, int2* __restrict__ seg,
    int* __restrict__ offs, int* __restrict__ rend)
{
    __shared__ int2 sorted[CAP];           // 32 KB
    __shared__ int hist[BS + 1];
    __shared__ int cursor[BS];

    const int b = blockIdx.x;
    const int t = threadIdx.x;
    const int s = b * CAP;
    const int cnt = bcur[b] - s;

    if (t < BS + 1) hist[t] = 0;
    __syncthreads();

    int2 ed[8];
    #pragma unroll
    for (int j = 0; j < 8; ++j) {
        int idx = t + j * 512;
        if (idx < cnt) {
            ed[j] = seg[s + idx];
            atomicAdd(&hist[ed[j].x & 255], 1);
        }
    }
    __syncthreads();

    if (t == 0) {
        int run = 0;
        for (int i = 0; i < BS; ++i) { int c = hist[i]; hist[i] = run; run += c; }
        hist[BS] = run;
    }
    __syncthreads();

    if (t < BS) {
        cursor[t] = hist[t];
        offs[b * BS + t] = s + hist[t];
        rend[b * BS + t] = s + hist[t + 1];
    }
    __syncthreads();

    #pragma unroll
    for (int j = 0; j < 8; ++j) {
        int idx = t + j * 512;
        if (idx < cnt) {
            int pos = atomicAdd(&cursor[ed[j].x & 255], 1);
            int2 cv;
            cv.x = (int)(((unsigned)ed[j].x) >> 8);   // col
            cv.y = ed[j].y;                            // val bits
            sorted[pos] = cv;
        }
    }
    __syncthreads();

    #pragma unroll
    for (int j = 0; j < 8; ++j) {
        int idx = t + j * 512;
        if (idx < cnt) seg[s + idx] = sorted[idx];
    }
}

// ---------------- SpMM: one wave per row, register accumulation, 8-deep ------
__global__ __launch_bounds__(256) void spmm_row_kernel(
    const int* __restrict__ offs, const int* __restrict__ rend,
    const int2* __restrict__ seg,
    const float* __restrict__ x, float* __restrict__ y,
    const float* __restrict__ bias, int N)
{
    const int lane = threadIdx.x & 63;
    int r = blockIdx.x * 4 + (threadIdx.x >> 6);
    if (r >= N) return;
    r = __builtin_amdgcn_readfirstlane(r);

    const int s = offs[r];
    const int e = rend[r];
    const float* xl = x + lane;

    float acc = 0.f;
    int i0 = s;
    for (; i0 + 8 <= e; i0 += 8) {
        int2 c0 = seg[i0    ], c1 = seg[i0 + 1];
        int2 c2 = seg[i0 + 2], c3 = seg[i0 + 3];
        int2 c4 = seg[i0 + 4], c5 = seg[i0 + 5];
        int2 c6 = seg[i0 + 6], c7 = seg[i0 + 7];
        float x0 = xl[(size_t)c0.x * OUT_CH];
        float x1 = xl[(size_t)c1.x * OUT_CH];
        float x2 = xl[(size_t)c2.x * OUT_CH];
        float x3 = xl[(size_t)c3.x * OUT_CH];
        float x4 = xl[(size_t)c4.x * OUT_CH];
        float x5 = xl[(size_t)c5.x * OUT_CH];
        float x6 = xl[(size_t)c6.x * OUT_CH];
        float x7 = xl[(size_t)c7.x * OUT_CH];
        acc = fmaf(__int_as_float(c0.y), x0, acc);
        acc = fmaf(__int_as_float(c1.y), x1, acc);
        acc = fmaf(__int_as_float(c2.y), x2, acc);
        acc = fmaf(__int_as_float(c3.y), x3, acc);
        acc = fmaf(__int_as_float(c4.y), x4, acc);
        acc = fmaf(__int_as_float(c5.y), x5, acc);
        acc = fmaf(__int_as_float(c6.y), x6, acc);
        acc = fmaf(__int_as_float(c7.y), x7, acc);
    }
    if (i0 < e) {
        #pragma unroll
        for (int j = 0; j < 8; ++j) {
            int ij = i0 + j < e ? i0 + j : e - 1;
            int2 c = seg[ij];
            float w = (i0 + j < e) ? __int_as_float(c.y) : 0.f;
            float xv = xl[(size_t)c.x * OUT_CH];
            acc = fmaf(w, xv, acc);
        }
    }
    if (bias) acc += bias[lane];
    y[(size_t)r * OUT_CH + lane] = acc;
}

// ---------------- launch -----------------------------------------------------
static inline size_t align_up(size_t v) { return (v + 255) & ~(size_t)255; }

extern "C" void kernel_launch(void* const* d_in, const int* in_sizes, int n_in,
                              void* d_out, int out_size, void* d_ws, size_t ws_size,
                              hipStream_t stream)
{
    const int*   adj  = (const int*)d_in[0];    // [2,E]
    const float* vals = (const float*)d_in[1];  // [E]
    const float* feat = (const float*)d_in[2];  // [N,512]
    const float* Wm   = (const float*)d_in[3];  // [512,64]
    const float* bias = (const float*)d_in[4];  // [64]

    const int E = in_sizes[1];
    const int N = in_sizes[2] / IN_CH;
    const int* rows  = adj;
    const int* colsI = adj + E;

    char* w = (char*)d_ws;
    size_t o = 0;
    float* B0   = (float*)(w + o); o += align_up((size_t)N * OUT_CH * sizeof(float));
    __hip_bfloat16* Wf = (__hip_bfloat16*)(w + o); o += align_up((size_t)IN_CH * OUT_CH * sizeof(__hip_bfloat16));
    int*   bcur = (int*)  (w + o); o += align_up(NB * sizeof(int));
    int*   offs = (int*)  (w + o); o += align_up((size_t)NB * BS * sizeof(int));
    int*   rend = (int*)  (w + o); o += align_up((size_t)NB * BS * sizeof(int));
    int2*  seg  = (int2*) (w + o); o += align_up((size_t)NB * CAP * sizeof(int2));
    (void)ws_size; (void)n_in; (void)out_size;

    float* out = (float*)d_out;

    // 0. W -> bf16 B-fragments, bcur init
    prep_kernel<<<8, 512, 0, stream>>>(Wm, Wf, bcur);

    // 1. dense projection -> d_out
    gemm_kernel<<<(N + 63) / 64, 256, 0, stream>>>(feat, Wf, out, N);

    // 2. CSR build: fixed-capacity bucket scatter + per-bucket LDS sort
    bucket_scatter_kernel<<<(E + CHUNK - 1) / CHUNK, 512, 0, stream>>>(
        rows, colsI, vals, bcur, seg, E);
    sort_kernel<<<NB, 512, 0, stream>>>(bcur, seg, offs, rend);

    // 3. two propagation rounds (bias fused into the last)
    spmm_row_kernel<<<(N + 3) / 4, 256, 0, stream>>>(offs, rend, seg, out, B0, nullptr, N);
    spmm_row_kernel<<<(N + 3) / 4, 256, 0, stream>>>(offs, rend, seg, B0, out, bias, N);
}

// Round 7
// 151.441 us; speedup vs baseline: 7.6986x; 1.0399x over previous
//
#include <hip/hip_runtime.h>
#include <hip/hip_bf16.h>

typedef __attribute__((ext_vector_type(8))) __bf16 bf16x8;
typedef __attribute__((ext_vector_type(4))) float f32x4;

#define IN_CH 512
#define OUT_CH 64
#define BS 98           // rows per bucket (rowres fits in 8 bits)
#define NB 512          // buckets; BS*NB = 50176 >= N
#define CHUNK 4096      // edges per scatter block (512 thr x 8)
#define CAP 4096        // fixed slots per bucket (mean 3125, +17 sigma)
#define KC 64           // A-tile chunk: 64 rows x 64 floats = 16 KB
#define NCHUNK (IN_CH / KC)

// ---------------- prep: W -> MFMA B-fragments (bf16) + bcur init -------------
// Wf layout: frag (ct,ks) at [(ct*16+ks)*64 + lane]*8 .. +7  (bf16 elements)
// lane l of frag (ct,ks) holds W[k = ks*32 + (l>>4)*8 + j][n = ct*16 + (l&15)]
__global__ __launch_bounds__(512) void prep_kernel(
    const float* __restrict__ W, __hip_bfloat16* __restrict__ Wf,
    int* __restrict__ bcur)
{
    const int t = blockIdx.x * 512 + threadIdx.x;   // 0..4095
    if (t < NB) bcur[t] = t * CAP;
    const int ct = t >> 10;          // 0..3
    const int rem = t & 1023;
    const int ks = rem >> 6;         // 0..15
    const int l = rem & 63;          // lane
    const int col = ct * 16 + (l & 15);
    const int kb = ks * 32 + (l >> 4) * 8;
    __hip_bfloat16* dst = Wf + (size_t)t * 8;
    #pragma unroll
    for (int j = 0; j < 8; ++j)
        dst[j] = (__hip_bfloat16)W[(size_t)(kb + j) * OUT_CH + col];
}

// ---------------- GEMM: LDS-staged A (reg-split, XOR-swizzled), MFMA ---------
// A-tile chunk: [64 rows][16 x 16B-blocks]; LDS position of block (row,blk)
// is row*16 + (blk ^ (row&7)) -> 2-way bank aliasing only (free).
__global__ __launch_bounds__(256) void gemm_kernel(
    const float* __restrict__ A, const __hip_bfloat16* __restrict__ Wf,
    float* __restrict__ out, int N)
{
    __shared__ __align__(16) float At[2][64 * KC];   // 2 x 16 KB

    const int tid = threadIdx.x;
    const int lane = tid & 63;
    const int wave = tid >> 6;
    const int row0 = blockIdx.x * 64;
    const int col = lane & 15;
    const bf16x8* wf = (const bf16x8*)Wf;

    // per-thread staging map: float4 index f = i*256+tid -> row=f>>4, blk=f&15
    int srow[4], sblk[4];
    const float* sptr[4];
    #pragma unroll
    for (int i = 0; i < 4; ++i) {
        int f = i * 256 + tid;
        srow[i] = f >> 4;
        sblk[i] = f & 15;
        int rg = row0 + srow[i]; rg = rg < N ? rg : N - 1;
        sptr[i] = A + (size_t)rg * IN_CH + sblk[i] * 4;
    }

    float4 sreg[4];
    #pragma unroll
    for (int i = 0; i < 4; ++i) sreg[i] = *(const float4*)(sptr[i]);      // chunk 0
    #pragma unroll
    for (int i = 0; i < 4; ++i)
        *(f32x4*)(&At[0][(srow[i] * 16 + (sblk[i] ^ (srow[i] & 7))) * 4]) =
            *(f32x4*)(&sreg[i]);
    __syncthreads();

    f32x4 acc0 = {0.f,0.f,0.f,0.f}, acc1 = {0.f,0.f,0.f,0.f};
    f32x4 acc2 = {0.f,0.f,0.f,0.f}, acc3 = {0.f,0.f,0.f,0.f};

    const int rloc = wave * 16 + (lane & 15);
    const int sw = rloc & 7;
    const int kqb = (lane >> 4) * 2;   // base 16B-block within k-step

    for (int c = 0; c < NCHUNK; ++c) {
        const int b = c & 1;
        if (c + 1 < NCHUNK) {
            #pragma unroll
            for (int i = 0; i < 4; ++i)
                sreg[i] = *(const float4*)(sptr[i] + (c + 1) * KC);
        }
        #pragma unroll
        for (int s = 0; s < 2; ++s) {
            int ks = c * 2 + s;
            int blk = s * 8 + kqb;
            f32x4 p = *(const f32x4*)(&At[b][(rloc * 16 + (blk ^ sw)) * 4]);
            f32x4 q = *(const f32x4*)(&At[b][(rloc * 16 + ((blk + 1) ^ sw)) * 4]);
            bf16x8 a;
            a[0]=(__bf16)p[0]; a[1]=(__bf16)p[1]; a[2]=(__bf16)p[2]; a[3]=(__bf16)p[3];
            a[4]=(__bf16)q[0]; a[5]=(__bf16)q[1]; a[6]=(__bf16)q[2]; a[7]=(__bf16)q[3];
            bf16x8 b0 = wf[(0 * 16 + ks) * 64 + lane];
            bf16x8 b1 = wf[(1 * 16 + ks) * 64 + lane];
            bf16x8 b2 = wf[(2 * 16 + ks) * 64 + lane];
            bf16x8 b3 = wf[(3 * 16 + ks) * 64 + lane];
            acc0 = __builtin_amdgcn_mfma_f32_16x16x32_bf16(a, b0, acc0, 0, 0, 0);
            acc1 = __builtin_amdgcn_mfma_f32_16x16x32_bf16(a, b1, acc1, 0, 0, 0);
            acc2 = __builtin_amdgcn_mfma_f32_16x16x32_bf16(a, b2, acc2, 0, 0, 0);
            acc3 = __builtin_amdgcn_mfma_f32_16x16x32_bf16(a, b3, acc3, 0, 0, 0);
        }
        if (c + 1 < NCHUNK) {
            #pragma unroll
            for (int i = 0; i < 4; ++i)
                *(f32x4*)(&At[b ^ 1][(srow[i] * 16 + (sblk[i] ^ (srow[i] & 7))) * 4]) =
                    *(f32x4*)(&sreg[i]);
        }
        __syncthreads();
    }

    int rr = row0 + wave * 16 + (lane >> 4) * 4;
    for (int i = 0; i < 4; ++i) {
        int r = rr + i;
        if (r < N) {
            float* o = out + (size_t)r * OUT_CH;
            o[col]      = acc0[i];
            o[col + 16] = acc1[i];
            o[col + 32] = acc2[i];
            o[col + 48] = acc3[i];
        }
    }
}

// ---------------- bucket scatter: group 4096 edges per block -----------------
__global__ __launch_bounds__(512) void bucket_scatter_kernel(
    const int* __restrict__ rows, const int* __restrict__ cols,
    const float* __restrict__ vals, int* __restrict__ bcur,
    int2* __restrict__ seg, int E)
{
    __shared__ int hist[NB];
    __shared__ int posBase[NB];
    const int tid = threadIdx.x;
    const int c0 = blockIdx.x * CHUNK;

    hist[tid] = 0;
    __syncthreads();

    int myb[8], mypack[8]; float myval[8];
    #pragma unroll
    for (int i = 0; i < 8; ++i) {
        int e = c0 + i * 512 + tid;
        myb[i] = -1;
        if (e < E) {
            int r = rows[e];
            int b = r / BS;
            int rr = r - b * BS;
            myb[i] = b;
            mypack[i] = (cols[e] << 8) | rr;
            myval[i] = vals[e];
            atomicAdd(&hist[b], 1);
        }
    }
    __syncthreads();

    int h = hist[tid];
    if (h) posBase[tid] = atomicAdd(&bcur[tid], h);
    hist[tid] = 0;   // reuse as local cursor
    __syncthreads();

    #pragma unroll
    for (int i = 0; i < 8; ++i) {
        if (myb[i] >= 0) {
            int p = posBase[myb[i]] + atomicAdd(&hist[myb[i]], 1);
            int2 cv; cv.x = mypack[i]; cv.y = __float_as_int(myval[i]);
            seg[p] = cv;
        }
    }
}

// ---------------- per-bucket LDS sort -> per-row offs/rend (in-place) --------
__global__ __launch_bounds__(512) void sort_kernel(
    const int* __restrict__ bcur, int2* __restrict__ seg,
    int* __restrict__ offs, int* __restrict__ rend)
{
    __shared__ int2 sorted[CAP];           // 32 KB
    __shared__ int hist[BS + 1];
    __shared__ int cursor[BS];

    const int b = blockIdx.x;
    const int t = threadIdx.x;
    const int s = b * CAP;
    const int cnt = bcur[b] - s;

    if (t < BS + 1) hist[t] = 0;
    __syncthreads();

    int2 ed[8];
    #pragma unroll
    for (int j = 0; j < 8; ++j) {
        int idx = t + j * 512;
        if (idx < cnt) {
            ed[j] = seg[s + idx];
            atomicAdd(&hist[ed[j].x & 255], 1);
        }
    }
    __syncthreads();

    if (t == 0) {
        int run = 0;
        for (int i = 0; i < BS; ++i) { int c = hist[i]; hist[i] = run; run += c; }
        hist[BS] = run;
    }
    __syncthreads();

    if (t < BS) {
        cursor[t] = hist[t];
        offs[b * BS + t] = s + hist[t];
        rend[b * BS + t] = s + hist[t + 1];
    }
    __syncthreads();

    #pragma unroll
    for (int j = 0; j < 8; ++j) {
        int idx = t + j * 512;
        if (idx < cnt) {
            int pos = atomicAdd(&cursor[ed[j].x & 255], 1);
            int2 cv;
            cv.x = (int)(((unsigned)ed[j].x) >> 8);   // col
            cv.y = ed[j].y;                            // val bits
            sorted[pos] = cv;
        }
    }
    __syncthreads();

    #pragma unroll
    for (int j = 0; j < 8; ++j) {
        int idx = t + j * 512;
        if (idx < cnt) seg[s + idx] = sorted[idx];
    }
}

// ---------------- SpMM: one wave per row, register accumulation, 8-deep ------
__global__ __launch_bounds__(256) void spmm_row_kernel(
    const int* __restrict__ offs, const int* __restrict__ rend,
    const int2* __restrict__ seg,
    const float* __restrict__ x, float* __restrict__ y,
    const float* __restrict__ bias, int N)
{
    const int lane = threadIdx.x & 63;
    int r = blockIdx.x * 4 + (threadIdx.x >> 6);
    if (r >= N) return;
    r = __builtin_amdgcn_readfirstlane(r);

    const int s = offs[r];
    const int e = rend[r];
    const float* xl = x + lane;

    float acc = 0.f;
    int i0 = s;
    for (; i0 + 8 <= e; i0 += 8) {
        int2 c0 = seg[i0    ], c1 = seg[i0 + 1];
        int2 c2 = seg[i0 + 2], c3 = seg[i0 + 3];
        int2 c4 = seg[i0 + 4], c5 = seg[i0 + 5];
        int2 c6 = seg[i0 + 6], c7 = seg[i0 + 7];
        float x0 = xl[(size_t)c0.x * OUT_CH];
        float x1 = xl[(size_t)c1.x * OUT_CH];
        float x2 = xl[(size_t)c2.x * OUT_CH];
        float x3 = xl[(size_t)c3.x * OUT_CH];
        float x4 = xl[(size_t)c4.x * OUT_CH];
        float x5 = xl[(size_t)c5.x * OUT_CH];
        float x6 = xl[(size_t)c6.x * OUT_CH];
        float x7 = xl[(size_t)c7.x * OUT_CH];
        acc = fmaf(__int_as_float(c0.y), x0, acc);
        acc = fmaf(__int_as_float(c1.y), x1, acc);
        acc = fmaf(__int_as_float(c2.y), x2, acc);
        acc = fmaf(__int_as_float(c3.y), x3, acc);
        acc = fmaf(__int_as_float(c4.y), x4, acc);
        acc = fmaf(__int_as_float(c5.y), x5, acc);
        acc = fmaf(__int_as_float(c6.y), x6, acc);
        acc = fmaf(__int_as_float(c7.y), x7, acc);
    }
    if (i0 < e) {
        #pragma unroll
        for (int j = 0; j < 8; ++j) {
            int ij = i0 + j < e ? i0 + j : e - 1;
            int2 c = seg[ij];
            float w = (i0 + j < e) ? __int_as_float(c.y) : 0.f;
            float xv = xl[(size_t)c.x * OUT_CH];
            acc = fmaf(w, xv, acc);
        }
    }
    if (bias) acc += bias[lane];
    y[(size_t)r * OUT_CH + lane] = acc;
}

// ---------------- launch -----------------------------------------------------
static inline size_t align_up(size_t v) { return (v + 255) & ~(size_t)255; }

extern "C" void kernel_launch(void* const* d_in, const int* in_sizes, int n_in,
                              void* d_out, int out_size, void* d_ws, size_t ws_size,
                              hipStream_t stream)
{
    const int*   adj  = (const int*)d_in[0];    // [2,E]
    const float* vals = (const float*)d_in[1];  // [E]
    const float* feat = (const float*)d_in[2];  // [N,512]
    const float* Wm   = (const float*)d_in[3];  // [512,64]
    const float* bias = (const float*)d_in[4];  // [64]

    const int E = in_sizes[1];
    const int N = in_sizes[2] / IN_CH;
    const int* rows  = adj;
    const int* colsI = adj + E;

    char* w = (char*)d_ws;
    size_t o = 0;
    float* B0   = (float*)(w + o); o += align_up((size_t)N * OUT_CH * sizeof(float));
    __hip_bfloat16* Wf = (__hip_bfloat16*)(w + o); o += align_up((size_t)IN_CH * OUT_CH * sizeof(__hip_bfloat16));
    int*   bcur = (int*)  (w + o); o += align_up(NB * sizeof(int));
    int*   offs = (int*)  (w + o); o += align_up((size_t)NB * BS * sizeof(int));
    int*   rend = (int*)  (w + o); o += align_up((size_t)NB * BS * sizeof(int));
    int2*  seg  = (int2*) (w + o); o += align_up((size_t)NB * CAP * sizeof(int2));
    (void)ws_size; (void)n_in; (void)out_size;

    float* out = (float*)d_out;

    // 0. W -> bf16 B-fragments, bcur init
    prep_kernel<<<8, 512, 0, stream>>>(Wm, Wf, bcur);

    // 1. dense projection -> d_out
    gemm_kernel<<<(N + 63) / 64, 256, 0, stream>>>(feat, Wf, out, N);

    // 2. CSR build: fixed-capacity bucket scatter + per-bucket LDS sort
    bucket_scatter_kernel<<<(E + CHUNK - 1) / CHUNK, 512, 0, stream>>>(
        rows, colsI, vals, bcur, seg, E);
    sort_kernel<<<NB, 512, 0, stream>>>(bcur, seg, offs, rend);

    // 3. two propagation rounds (bias fused into the last)
    spmm_row_kernel<<<(N + 3) / 4, 256, 0, stream>>>(offs, rend, seg, out, B0, nullptr, N);
    spmm_row_kernel<<<(N + 3) / 4, 256, 0, stream>>>(offs, rend, seg, B0, out, bias, N);
}

// Round 8
// 131.195 us; speedup vs baseline: 8.8867x; 1.1543x over previous
//
#include <hip/hip_runtime.h>
#include <hip/hip_bf16.h>

typedef __attribute__((ext_vector_type(8))) __bf16 bf16x8;
typedef __attribute__((ext_vector_type(4))) float f32x4;

#define IN_CH 512
#define OUT_CH 64
#define BS 98           // rows per bucket (rowres fits in 8 bits)
#define NB 512          // buckets; BS*NB = 50176 >= N
#define CHUNK 4096      // edges per scatter block (512 thr x 8)
#define CAP 4096        // fixed slots per bucket (mean 3125, +17 sigma)

__device__ inline unsigned short f2bf(float f) {
    __hip_bfloat16 h = __float2bfloat16(f);
    return __builtin_bit_cast(unsigned short, h);
}

// ---------------- prep: W -> MFMA B-fragments (bf16) + bcur init -------------
// Wf layout: frag (ct,ks) at [(ct*16+ks)*64 + lane]*8 .. +7  (bf16 elements)
// lane l of frag (ct,ks) holds W[k = ks*32 + (l>>4)*8 + j][n = ct*16 + (l&15)]
__global__ __launch_bounds__(512) void prep_kernel(
    const float* __restrict__ W, __hip_bfloat16* __restrict__ Wf,
    int* __restrict__ bcur)
{
    const int t = blockIdx.x * 512 + threadIdx.x;   // 0..4095
    if (t < NB) bcur[t] = t * CAP;
    const int ct = t >> 10;          // 0..3
    const int rem = t & 1023;
    const int ks = rem >> 6;         // 0..15
    const int l = rem & 63;          // lane
    const int col = ct * 16 + (l & 15);
    const int kb = ks * 32 + (l >> 4) * 8;
    __hip_bfloat16* dst = Wf + (size_t)t * 8;
    #pragma unroll
    for (int j = 0; j < 8; ++j)
        dst[j] = (__hip_bfloat16)W[(size_t)(kb + j) * OUT_CH + col];
}

// ---------------- GEMM: whole 32-row A-tile staged bf16, single barrier ------
// LDS layout: row r (0..31) occupies 1024B; 16B block b stored at b ^ (r&7).
__global__ __launch_bounds__(128) void gemm_kernel(
    const float* __restrict__ A, const bf16x8* __restrict__ wf,
    __hip_bfloat16* __restrict__ outb, int N)
{
    __shared__ __align__(16) char Abf[32 * 1024];   // 32 KB

    const int tid = threadIdx.x;
    const int row0 = blockIdx.x * 32;

    // ---- stage: 32 rows x 128 float4; 128 threads x 32 float4, 8-deep ----
    #pragma unroll 1
    for (int ob = 0; ob < 4; ++ob) {
        float4 v[8];
        #pragma unroll
        for (int j = 0; j < 8; ++j) {
            int f = (ob * 8 + j) * 128 + tid;
            int row = f >> 7, c4 = f & 127;
            int rg = row0 + row; rg = rg < N ? rg : N - 1;
            v[j] = *(const float4*)(A + (size_t)rg * IN_CH + c4 * 4);
        }
        #pragma unroll
        for (int j = 0; j < 8; ++j) {
            int f = (ob * 8 + j) * 128 + tid;
            int row = f >> 7, c4 = f & 127;
            int blk = c4 >> 1, half = c4 & 1;
            ushort4 h;
            h.x = f2bf(v[j].x); h.y = f2bf(v[j].y);
            h.z = f2bf(v[j].z); h.w = f2bf(v[j].w);
            *(ushort4*)(Abf + row * 1024 + ((blk ^ (row & 7)) << 4) + (half << 3)) = h;
        }
    }
    __syncthreads();

    const int lane = tid & 63;
    const int wave = tid >> 6;
    const int arow = wave * 16 + (lane & 15);
    const int kgb = lane >> 4;            // 0..3

    // all 16 A-fragments to registers (64 VGPR)
    bf16x8 a[16];
    #pragma unroll
    for (int ks = 0; ks < 16; ++ks)
        a[ks] = *(const bf16x8*)(Abf + arow * 1024 +
                                 (((ks * 4 + kgb) ^ (arow & 7)) << 4));

    const int colb = lane & 15;
    const int rr = row0 + wave * 16 + (lane >> 4) * 4;
    #pragma unroll 1
    for (int ct = 0; ct < 4; ++ct) {
        bf16x8 w[16];
        #pragma unroll
        for (int ks = 0; ks < 16; ++ks) w[ks] = wf[(ct * 16 + ks) * 64 + lane];
        f32x4 acc = {0.f, 0.f, 0.f, 0.f};
        #pragma unroll
        for (int ks = 0; ks < 16; ++ks)
            acc = __builtin_amdgcn_mfma_f32_16x16x32_bf16(a[ks], w[ks], acc, 0, 0, 0);
        int col = ct * 16 + colb;
        #pragma unroll
        for (int i = 0; i < 4; ++i) {
            int r = rr + i;
            if (r < N)
                outb[(size_t)r * OUT_CH + col] = __float2bfloat16(acc[i]);
        }
    }
}

// ---------------- bucket scatter: group 4096 edges per block -----------------
__global__ __launch_bounds__(512) void bucket_scatter_kernel(
    const int* __restrict__ rows, const int* __restrict__ cols,
    const float* __restrict__ vals, int* __restrict__ bcur,
    int2* __restrict__ seg, int E)
{
    __shared__ int hist[NB];
    __shared__ int posBase[NB];
    const int tid = threadIdx.x;
    const int c0 = blockIdx.x * CHUNK;

    hist[tid] = 0;
    __syncthreads();

    int myb[8], mypack[8]; float myval[8];
    #pragma unroll
    for (int i = 0; i < 8; ++i) {
        int e = c0 + i * 512 + tid;
        myb[i] = -1;
        if (e < E) {
            int r = rows[e];
            int b = r / BS;
            int rr = r - b * BS;
            myb[i] = b;
            mypack[i] = (cols[e] << 8) | rr;
            myval[i] = vals[e];
            atomicAdd(&hist[b], 1);
        }
    }
    __syncthreads();

    int h = hist[tid];
    if (h) posBase[tid] = atomicAdd(&bcur[tid], h);
    hist[tid] = 0;   // reuse as local cursor
    __syncthreads();

    #pragma unroll
    for (int i = 0; i < 8; ++i) {
        if (myb[i] >= 0) {
            int p = posBase[myb[i]] + atomicAdd(&hist[myb[i]], 1);
            int2 cv; cv.x = mypack[i]; cv.y = __float_as_int(myval[i]);
            seg[p] = cv;
        }
    }
}

// ---------------- per-bucket LDS sort -> per-row offs/rend (in-place) --------
__global__ __launch_bounds__(512) void sort_kernel(
    const int* __restrict__ bcur, int2* __restrict__ seg,
    int* __restrict__ offs, int* __restrict__ rend)
{
    __shared__ int2 sorted[CAP];           // 32 KB
    __shared__ int hist[BS + 1];
    __shared__ int cursor[BS];

    const int b = blockIdx.x;
    const int t = threadIdx.x;
    const int s = b * CAP;
    const int cnt = bcur[b] - s;

    if (t < BS + 1) hist[t] = 0;
    __syncthreads();

    int2 ed[8];
    #pragma unroll
    for (int j = 0; j < 8; ++j) {
        int idx = t + j * 512;
        if (idx < cnt) {
            ed[j] = seg[s + idx];
            atomicAdd(&hist[ed[j].x & 255], 1);
        }
    }
    __syncthreads();

    if (t == 0) {
        int run = 0;
        for (int i = 0; i < BS; ++i) { int c = hist[i]; hist[i] = run; run += c; }
        hist[BS] = run;
    }
    __syncthreads();

    if (t < BS) {
        cursor[t] = hist[t];
        offs[b * BS + t] = s + hist[t];
        rend[b * BS + t] = s + hist[t + 1];
    }
    __syncthreads();

    #pragma unroll
    for (int j = 0; j < 8; ++j) {
        int idx = t + j * 512;
        if (idx < cnt) {
            int pos = atomicAdd(&cursor[ed[j].x & 255], 1);
            int2 cv;
            cv.x = (int)(((unsigned)ed[j].x) >> 8);   // col
            cv.y = ed[j].y;                            // val bits
            sorted[pos] = cv;
        }
    }
    __syncthreads();

    #pragma unroll
    for (int j = 0; j < 8; ++j) {
        int idx = t + j * 512;
        if (idx < cnt) seg[s + idx] = sorted[idx];
    }
}

// ---------------- SpMM: one wave per row, reg accumulation, bf16 x -----------
__global__ __launch_bounds__(256) void spmm_row_kernel(
    const int* __restrict__ offs, const int* __restrict__ rend,
    const int2* __restrict__ seg,
    const __hip_bfloat16* __restrict__ x,
    __hip_bfloat16* __restrict__ yb,      // bf16 out (pass 1)
    float* __restrict__ yf,               // fp32 out (final pass), or null
    const float* __restrict__ bias, int N)
{
    const int lane = threadIdx.x & 63;
    int r = blockIdx.x * 4 + (threadIdx.x >> 6);
    if (r >= N) return;
    r = __builtin_amdgcn_readfirstlane(r);

    const int s = offs[r];
    const int e = rend[r];
    const __hip_bfloat16* xl = x + lane;

    float acc = 0.f;
    int i0 = s;
    for (; i0 + 8 <= e; i0 += 8) {
        int2 c0 = seg[i0    ], c1 = seg[i0 + 1];
        int2 c2 = seg[i0 + 2], c3 = seg[i0 + 3];
        int2 c4 = seg[i0 + 4], c5 = seg[i0 + 5];
        int2 c6 = seg[i0 + 6], c7 = seg[i0 + 7];
        float x0 = __bfloat162float(xl[(size_t)c0.x * OUT_CH]);
        float x1 = __bfloat162float(xl[(size_t)c1.x * OUT_CH]);
        float x2 = __bfloat162float(xl[(size_t)c2.x * OUT_CH]);
        float x3 = __bfloat162float(xl[(size_t)c3.x * OUT_CH]);
        float x4 = __bfloat162float(xl[(size_t)c4.x * OUT_CH]);
        float x5 = __bfloat162float(xl[(size_t)c5.x * OUT_CH]);
        float x6 = __bfloat162float(xl[(size_t)c6.x * OUT_CH]);
        float x7 = __bfloat162float(xl[(size_t)c7.x * OUT_CH]);
        acc = fmaf(__int_as_float(c0.y), x0, acc);
        acc = fmaf(__int_as_float(c1.y), x1, acc);
        acc = fmaf(__int_as_float(c2.y), x2, acc);
        acc = fmaf(__int_as_float(c3.y), x3, acc);
        acc = fmaf(__int_as_float(c4.y), x4, acc);
        acc = fmaf(__int_as_float(c5.y), x5, acc);
        acc = fmaf(__int_as_float(c6.y), x6, acc);
        acc = fmaf(__int_as_float(c7.y), x7, acc);
    }
    if (i0 < e) {
        #pragma unroll
        for (int j = 0; j < 8; ++j) {
            int ij = i0 + j < e ? i0 + j : e - 1;
            int2 c = seg[ij];
            float w = (i0 + j < e) ? __int_as_float(c.y) : 0.f;
            float xv = __bfloat162float(xl[(size_t)c.x * OUT_CH]);
            acc = fmaf(w, xv, acc);
        }
    }
    if (yf) yf[(size_t)r * OUT_CH + lane] = acc + bias[lane];
    else    yb[(size_t)r * OUT_CH + lane] = __float2bfloat16(acc);
}

// ---------------- launch -----------------------------------------------------
static inline size_t align_up(size_t v) { return (v + 255) & ~(size_t)255; }

extern "C" void kernel_launch(void* const* d_in, const int* in_sizes, int n_in,
                              void* d_out, int out_size, void* d_ws, size_t ws_size,
                              hipStream_t stream)
{
    const int*   adj  = (const int*)d_in[0];    // [2,E]
    const float* vals = (const float*)d_in[1];  // [E]
    const float* feat = (const float*)d_in[2];  // [N,512]
    const float* Wm   = (const float*)d_in[3];  // [512,64]
    const float* bias = (const float*)d_in[4];  // [64]

    const int E = in_sizes[1];
    const int N = in_sizes[2] / IN_CH;
    const int* rows  = adj;
    const int* colsI = adj + E;

    char* w = (char*)d_ws;
    size_t o = 0;
    __hip_bfloat16* B0b = (__hip_bfloat16*)(w + o); o += align_up((size_t)N * OUT_CH * 2);
    __hip_bfloat16* Y1b = (__hip_bfloat16*)(w + o); o += align_up((size_t)N * OUT_CH * 2);
    __hip_bfloat16* Wf  = (__hip_bfloat16*)(w + o); o += align_up((size_t)IN_CH * OUT_CH * 2);
    int*   bcur = (int*)  (w + o); o += align_up(NB * sizeof(int));
    int*   offs = (int*)  (w + o); o += align_up((size_t)NB * BS * sizeof(int));
    int*   rend = (int*)  (w + o); o += align_up((size_t)NB * BS * sizeof(int));
    int2*  seg  = (int2*) (w + o); o += align_up((size_t)NB * CAP * sizeof(int2));
    (void)ws_size; (void)n_in; (void)out_size;

    // 0. W -> bf16 B-fragments, bcur init
    prep_kernel<<<8, 512, 0, stream>>>(Wm, Wf, bcur);

    // 1. dense projection -> B0b (bf16)
    gemm_kernel<<<(N + 31) / 32, 128, 0, stream>>>(
        feat, (const bf16x8*)Wf, B0b, N);

    // 2. CSR build: fixed-capacity bucket scatter + per-bucket LDS sort
    bucket_scatter_kernel<<<(E + CHUNK - 1) / CHUNK, 512, 0, stream>>>(
        rows, colsI, vals, bcur, seg, E);
    sort_kernel<<<NB, 512, 0, stream>>>(bcur, seg, offs, rend);

    // 3. two propagation rounds (bias fused into the last)
    spmm_row_kernel<<<(N + 3) / 4, 256, 0, stream>>>(
        offs, rend, seg, B0b, Y1b, nullptr, nullptr, N);
    spmm_row_kernel<<<(N + 3) / 4, 256, 0, stream>>>(
        offs, rend, seg, Y1b, nullptr, (float*)d_out, bias, N);
}

// Round 9
// 125.076 us; speedup vs baseline: 9.3214x; 1.0489x over previous
//
#include <hip/hip_runtime.h>
#include <hip/hip_bf16.h>

typedef __attribute__((ext_vector_type(8))) __bf16 bf16x8;
typedef __attribute__((ext_vector_type(4))) float f32x4;

#define IN_CH 512
#define OUT_CH 64
#define BS 98           // rows per bucket (rowres fits in 8 bits)
#define NB 512          // buckets; BS*NB = 50176 >= N
#define CHUNK 8192      // edges per scatter block (512 thr x 16)
#define CAP 4096        // fixed slots per bucket (mean 3125, +17 sigma)

__device__ inline unsigned short f2bf(float f) {
    __hip_bfloat16 h = __float2bfloat16(f);
    return __builtin_bit_cast(unsigned short, h);
}

// ---------------- prep: W -> MFMA B-fragments (bf16) + bcur init -------------
__global__ __launch_bounds__(512) void prep_kernel(
    const float* __restrict__ W, __hip_bfloat16* __restrict__ Wf,
    int* __restrict__ bcur)
{
    const int t = blockIdx.x * 512 + threadIdx.x;   // 0..4095
    if (t < NB) bcur[t] = t * CAP;
    const int ct = t >> 10;          // 0..3
    const int rem = t & 1023;
    const int ks = rem >> 6;         // 0..15
    const int l = rem & 63;          // lane
    const int col = ct * 16 + (l & 15);
    const int kb = ks * 32 + (l >> 4) * 8;
    __hip_bfloat16* dst = Wf + (size_t)t * 8;
    #pragma unroll
    for (int j = 0; j < 8; ++j)
        dst[j] = (__hip_bfloat16)W[(size_t)(kb + j) * OUT_CH + col];
}

// ---------------- GEMM: whole 32-row A-tile staged bf16, single barrier ------
__global__ __launch_bounds__(128) void gemm_kernel(
    const float* __restrict__ A, const bf16x8* __restrict__ wf,
    __hip_bfloat16* __restrict__ outb, int N)
{
    __shared__ __align__(16) char Abf[32 * 1024];   // 32 KB

    const int tid = threadIdx.x;
    const int row0 = blockIdx.x * 32;

    #pragma unroll 1
    for (int ob = 0; ob < 4; ++ob) {
        float4 v[8];
        #pragma unroll
        for (int j = 0; j < 8; ++j) {
            int f = (ob * 8 + j) * 128 + tid;
            int row = f >> 7, c4 = f & 127;
            int rg = row0 + row; rg = rg < N ? rg : N - 1;
            v[j] = *(const float4*)(A + (size_t)rg * IN_CH + c4 * 4);
        }
        #pragma unroll
        for (int j = 0; j < 8; ++j) {
            int f = (ob * 8 + j) * 128 + tid;
            int row = f >> 7, c4 = f & 127;
            int blk = c4 >> 1, half = c4 & 1;
            ushort4 h;
            h.x = f2bf(v[j].x); h.y = f2bf(v[j].y);
            h.z = f2bf(v[j].z); h.w = f2bf(v[j].w);
            *(ushort4*)(Abf + row * 1024 + ((blk ^ (row & 7)) << 4) + (half << 3)) = h;
        }
    }
    __syncthreads();

    const int lane = tid & 63;
    const int wave = tid >> 6;
    const int arow = wave * 16 + (lane & 15);
    const int kgb = lane >> 4;

    bf16x8 a[16];
    #pragma unroll
    for (int ks = 0; ks < 16; ++ks)
        a[ks] = *(const bf16x8*)(Abf + arow * 1024 +
                                 (((ks * 4 + kgb) ^ (arow & 7)) << 4));

    const int colb = lane & 15;
    const int rr = row0 + wave * 16 + (lane >> 4) * 4;
    #pragma unroll 1
    for (int ct = 0; ct < 4; ++ct) {
        bf16x8 w[16];
        #pragma unroll
        for (int ks = 0; ks < 16; ++ks) w[ks] = wf[(ct * 16 + ks) * 64 + lane];
        f32x4 acc = {0.f, 0.f, 0.f, 0.f};
        #pragma unroll
        for (int ks = 0; ks < 16; ++ks)
            acc = __builtin_amdgcn_mfma_f32_16x16x32_bf16(a[ks], w[ks], acc, 0, 0, 0);
        int col = ct * 16 + colb;
        #pragma unroll
        for (int i = 0; i < 4; ++i) {
            int r = rr + i;
            if (r < N)
                outb[(size_t)r * OUT_CH + col] = __float2bfloat16(acc[i]);
        }
    }
}

// ---------------- bucket scatter: 8192 edges/block, 16 consecutive/thread ----
__global__ __launch_bounds__(512) void bucket_scatter_kernel(
    const int* __restrict__ rows, const int* __restrict__ cols,
    const float* __restrict__ vals, int* __restrict__ bcur,
    int2* __restrict__ seg, int E)
{
    __shared__ int hist[NB];
    __shared__ int posBase[NB];
    const int tid = threadIdx.x;
    const int base = blockIdx.x * CHUNK + tid * 16;

    hist[tid] = 0;
    __syncthreads();

    int myb[16], mypack[16]; float myval[16];
    if (base + 16 <= E) {
        int4 r4[4], c4[4]; float4 v4[4];
        #pragma unroll
        for (int q = 0; q < 4; ++q) {
            r4[q] = *(const int4*)(rows + base + q * 4);
            c4[q] = *(const int4*)(cols + base + q * 4);
            v4[q] = *(const float4*)(vals + base + q * 4);
        }
        #pragma unroll
        for (int q = 0; q < 4; ++q) {
            int rr[4] = {r4[q].x, r4[q].y, r4[q].z, r4[q].w};
            int cc[4] = {c4[q].x, c4[q].y, c4[q].z, c4[q].w};
            float vv[4] = {v4[q].x, v4[q].y, v4[q].z, v4[q].w};
            #pragma unroll
            for (int u = 0; u < 4; ++u) {
                int j = q * 4 + u;
                int r = rr[u];
                int b = r / BS;
                myb[j] = b;
                mypack[j] = (cc[u] << 8) | (r - b * BS);
                myval[j] = vv[u];
                atomicAdd(&hist[b], 1);
            }
        }
    } else {
        #pragma unroll
        for (int j = 0; j < 16; ++j) {
            int e = base + j;
            myb[j] = -1;
            if (e < E) {
                int r = rows[e];
                int b = r / BS;
                myb[j] = b;
                mypack[j] = (cols[e] << 8) | (r - b * BS);
                myval[j] = vals[e];
                atomicAdd(&hist[b], 1);
            }
        }
    }
    __syncthreads();

    int h = hist[tid];
    if (h) posBase[tid] = atomicAdd(&bcur[tid], h);
    hist[tid] = 0;   // reuse as local cursor
    __syncthreads();

    #pragma unroll
    for (int j = 0; j < 16; ++j) {
        if (myb[j] >= 0) {
            int p = posBase[myb[j]] + atomicAdd(&hist[myb[j]], 1);
            int2 cv; cv.x = mypack[j]; cv.y = __float_as_int(myval[j]);
            seg[p] = cv;
        }
    }
}

// ---------------- per-bucket LDS sort -> 4B compact entries + offs/rend ------
// Output entry: (col << 16) | bf16(val)   (decode: val = asfloat(p<<16))
__global__ __launch_bounds__(512) void sort_kernel(
    const int* __restrict__ bcur, const int2* __restrict__ seg,
    unsigned* __restrict__ segc,
    int* __restrict__ offs, int* __restrict__ rend)
{
    __shared__ unsigned sorted4[CAP];      // 16 KB
    __shared__ int hist[BS + 1];
    __shared__ int cursor[BS];

    const int b = blockIdx.x;
    const int t = threadIdx.x;
    const int s = b * CAP;
    const int cnt = bcur[b] - s;

    if (t < BS + 1) hist[t] = 0;
    __syncthreads();

    int2 ed[8];
    #pragma unroll
    for (int j = 0; j < 8; ++j) {
        int idx = t + j * 512;
        if (idx < cnt) {
            ed[j] = seg[s + idx];
            atomicAdd(&hist[ed[j].x & 255], 1);
        }
    }
    __syncthreads();

    if (t == 0) {
        int run = 0;
        for (int i = 0; i < BS; ++i) { int c = hist[i]; hist[i] = run; run += c; }
        hist[BS] = run;
    }
    __syncthreads();

    if (t < BS) {
        cursor[t] = hist[t];
        offs[b * BS + t] = s + hist[t];
        rend[b * BS + t] = s + hist[t + 1];
    }
    __syncthreads();

    #pragma unroll
    for (int j = 0; j < 8; ++j) {
        int idx = t + j * 512;
        if (idx < cnt) {
            int pos = atomicAdd(&cursor[ed[j].x & 255], 1);
            unsigned col = ((unsigned)ed[j].x) >> 8;
            sorted4[pos] = (col << 16) | f2bf(__int_as_float(ed[j].y));
        }
    }
    __syncthreads();

    #pragma unroll
    for (int j = 0; j < 8; ++j) {
        int idx = t + j * 512;
        if (idx < cnt) segc[s + idx] = sorted4[idx];
    }
}

// ---------------- SpMM: one wave per row, reg accumulation, 16-deep ----------
__global__ __launch_bounds__(256) void spmm_row_kernel(
    const int* __restrict__ offs, const int* __restrict__ rend,
    const unsigned* __restrict__ segc,
    const __hip_bfloat16* __restrict__ x,
    __hip_bfloat16* __restrict__ yb,      // bf16 out (pass 1)
    float* __restrict__ yf,               // fp32 out (final pass), or null
    const float* __restrict__ bias, int N)
{
    const int lane = threadIdx.x & 63;
    int r = blockIdx.x * 4 + (threadIdx.x >> 6);
    if (r >= N) return;
    r = __builtin_amdgcn_readfirstlane(r);

    const int s = offs[r];
    const int e = rend[r];
    const __hip_bfloat16* xl = x + lane;

    float acc = 0.f;
    int i0 = s;
    for (; i0 + 16 <= e; i0 += 16) {
        unsigned p[16];
        #pragma unroll
        for (int j = 0; j < 16; ++j) p[j] = segc[i0 + j];
        float xv[16];
        #pragma unroll
        for (int j = 0; j < 16; ++j)
            xv[j] = __bfloat162float(xl[(size_t)(p[j] >> 16) * OUT_CH]);
        #pragma unroll
        for (int j = 0; j < 16; ++j)
            acc = fmaf(__int_as_float(p[j] << 16), xv[j], acc);
    }
    if (i0 < e) {
        #pragma unroll
        for (int j = 0; j < 16; ++j) {
            int ij = i0 + j < e ? i0 + j : e - 1;
            unsigned p = segc[ij];
            float w = (i0 + j < e) ? __int_as_float(p << 16) : 0.f;
            float xv = __bfloat162float(xl[(size_t)(p >> 16) * OUT_CH]);
            acc = fmaf(w, xv, acc);
        }
    }
    if (yf) yf[(size_t)r * OUT_CH + lane] = acc + bias[lane];
    else    yb[(size_t)r * OUT_CH + lane] = __float2bfloat16(acc);
}

// ---------------- launch -----------------------------------------------------
static inline size_t align_up(size_t v) { return (v + 255) & ~(size_t)255; }

extern "C" void kernel_launch(void* const* d_in, const int* in_sizes, int n_in,
                              void* d_out, int out_size, void* d_ws, size_t ws_size,
                              hipStream_t stream)
{
    const int*   adj  = (const int*)d_in[0];    // [2,E]
    const float* vals = (const float*)d_in[1];  // [E]
    const float* feat = (const float*)d_in[2];  // [N,512]
    const float* Wm   = (const float*)d_in[3];  // [512,64]
    const float* bias = (const float*)d_in[4];  // [64]

    const int E = in_sizes[1];
    const int N = in_sizes[2] / IN_CH;
    const int* rows  = adj;
    const int* colsI = adj + E;

    char* w = (char*)d_ws;
    size_t o = 0;
    __hip_bfloat16* B0b = (__hip_bfloat16*)(w + o); o += align_up((size_t)N * OUT_CH * 2);
    __hip_bfloat16* Y1b = (__hip_bfloat16*)(w + o); o += align_up((size_t)N * OUT_CH * 2);
    __hip_bfloat16* Wf  = (__hip_bfloat16*)(w + o); o += align_up((size_t)IN_CH * OUT_CH * 2);
    int*      bcur = (int*)     (w + o); o += align_up(NB * sizeof(int));
    int*      offs = (int*)     (w + o); o += align_up((size_t)NB * BS * sizeof(int));
    int*      rend = (int*)     (w + o); o += align_up((size_t)NB * BS * sizeof(int));
    int2*     seg  = (int2*)    (w + o); o += align_up((size_t)NB * CAP * sizeof(int2));
    unsigned* segc = (unsigned*)(w + o); o += align_up((size_t)NB * CAP * sizeof(unsigned));
    (void)ws_size; (void)n_in; (void)out_size;

    // 0. W -> bf16 B-fragments, bcur init
    prep_kernel<<<8, 512, 0, stream>>>(Wm, Wf, bcur);

    // 1. dense projection -> B0b (bf16)
    gemm_kernel<<<(N + 31) / 32, 128, 0, stream>>>(
        feat, (const bf16x8*)Wf, B0b, N);

    // 2. CSR build: fixed-capacity bucket scatter + per-bucket LDS sort
    bucket_scatter_kernel<<<(E + CHUNK - 1) / CHUNK, 512, 0, stream>>>(
        rows, colsI, vals, bcur, seg, E);
    sort_kernel<<<NB, 512, 0, stream>>>(bcur, seg, segc, offs, rend);

    // 3. two propagation rounds (bias fused into the last)
    spmm_row_kernel<<<(N + 3) / 4, 256, 0, stream>>>(
        offs, rend, segc, B0b, Y1b, nullptr, nullptr, N);
    spmm_row_kernel<<<(N + 3) / 4, 256, 0, stream>>>(
        offs, rend, segc, Y1b, nullptr, (float*)d_out, bias, N);
}

// Round 10
// 117.793 us; speedup vs baseline: 9.8977x; 1.0618x over previous
//
#include <hip/hip_runtime.h>
#include <hip/hip_bf16.h>

typedef __attribute__((ext_vector_type(8))) __bf16 bf16x8;
typedef __attribute__((ext_vector_type(4))) float f32x4;

#define IN_CH 512
#define OUT_CH 64
#define BS 98           // rows per bucket (rowres fits in 8 bits)
#define NB 512          // buckets; BS*NB = 50176 >= N
#define CHUNK 8192      // edges per scatter block (512 thr x 16)
#define CAP 4096        // fixed slots per bucket (mean 3125, +17 sigma)

__device__ inline unsigned short f2bf(float f) {
    __hip_bfloat16 h = __float2bfloat16(f);
    return __builtin_bit_cast(unsigned short, h);
}
__device__ inline float bf2f(unsigned short u) {
    return __uint_as_float(((unsigned)u) << 16);
}

// ---------------- prep: W -> MFMA B-fragments (bf16) + bcur init -------------
__global__ __launch_bounds__(512) void prep_kernel(
    const float* __restrict__ W, __hip_bfloat16* __restrict__ Wf,
    int* __restrict__ bcur)
{
    const int t = blockIdx.x * 512 + threadIdx.x;   // 0..4095
    if (t < NB) bcur[t] = t * CAP;
    const int ct = t >> 10;          // 0..3
    const int rem = t & 1023;
    const int ks = rem >> 6;         // 0..15
    const int l = rem & 63;          // lane
    const int col = ct * 16 + (l & 15);
    const int kb = ks * 32 + (l >> 4) * 8;
    __hip_bfloat16* dst = Wf + (size_t)t * 8;
    #pragma unroll
    for (int j = 0; j < 8; ++j)
        dst[j] = (__hip_bfloat16)W[(size_t)(kb + j) * OUT_CH + col];
}

// ---------------- GEMM: whole 32-row A-tile staged bf16, single barrier ------
__global__ __launch_bounds__(128) void gemm_kernel(
    const float* __restrict__ A, const bf16x8* __restrict__ wf,
    __hip_bfloat16* __restrict__ outb, int N)
{
    __shared__ __align__(16) char Abf[32 * 1024];   // 32 KB

    const int tid = threadIdx.x;
    const int row0 = blockIdx.x * 32;

    #pragma unroll 1
    for (int ob = 0; ob < 4; ++ob) {
        float4 v[8];
        #pragma unroll
        for (int j = 0; j < 8; ++j) {
            int f = (ob * 8 + j) * 128 + tid;
            int row = f >> 7, c4 = f & 127;
            int rg = row0 + row; rg = rg < N ? rg : N - 1;
            v[j] = *(const float4*)(A + (size_t)rg * IN_CH + c4 * 4);
        }
        #pragma unroll
        for (int j = 0; j < 8; ++j) {
            int f = (ob * 8 + j) * 128 + tid;
            int row = f >> 7, c4 = f & 127;
            int blk = c4 >> 1, half = c4 & 1;
            ushort4 h;
            h.x = f2bf(v[j].x); h.y = f2bf(v[j].y);
            h.z = f2bf(v[j].z); h.w = f2bf(v[j].w);
            *(ushort4*)(Abf + row * 1024 + ((blk ^ (row & 7)) << 4) + (half << 3)) = h;
        }
    }
    __syncthreads();

    const int lane = tid & 63;
    const int wave = tid >> 6;
    const int arow = wave * 16 + (lane & 15);
    const int kgb = lane >> 4;

    bf16x8 a[16];
    #pragma unroll
    for (int ks = 0; ks < 16; ++ks)
        a[ks] = *(const bf16x8*)(Abf + arow * 1024 +
                                 (((ks * 4 + kgb) ^ (arow & 7)) << 4));

    const int colb = lane & 15;
    const int rr = row0 + wave * 16 + (lane >> 4) * 4;
    #pragma unroll 1
    for (int ct = 0; ct < 4; ++ct) {
        bf16x8 w[16];
        #pragma unroll
        for (int ks = 0; ks < 16; ++ks) w[ks] = wf[(ct * 16 + ks) * 64 + lane];
        f32x4 acc = {0.f, 0.f, 0.f, 0.f};
        #pragma unroll
        for (int ks = 0; ks < 16; ++ks)
            acc = __builtin_amdgcn_mfma_f32_16x16x32_bf16(a[ks], w[ks], acc, 0, 0, 0);
        int col = ct * 16 + colb;
        #pragma unroll
        for (int i = 0; i < 4; ++i) {
            int r = rr + i;
            if (r < N)
                outb[(size_t)r * OUT_CH + col] = __float2bfloat16(acc[i]);
        }
    }
}

// ---------------- bucket scatter: 8192 edges/block, 16 consecutive/thread ----
__global__ __launch_bounds__(512) void bucket_scatter_kernel(
    const int* __restrict__ rows, const int* __restrict__ cols,
    const float* __restrict__ vals, int* __restrict__ bcur,
    int2* __restrict__ seg, int E)
{
    __shared__ int hist[NB];
    __shared__ int posBase[NB];
    const int tid = threadIdx.x;
    const int base = blockIdx.x * CHUNK + tid * 16;

    hist[tid] = 0;
    __syncthreads();

    int myb[16], mypack[16]; float myval[16];
    if (base + 16 <= E) {
        int4 r4[4], c4[4]; float4 v4[4];
        #pragma unroll
        for (int q = 0; q < 4; ++q) {
            r4[q] = *(const int4*)(rows + base + q * 4);
            c4[q] = *(const int4*)(cols + base + q * 4);
            v4[q] = *(const float4*)(vals + base + q * 4);
        }
        #pragma unroll
        for (int q = 0; q < 4; ++q) {
            int rr[4] = {r4[q].x, r4[q].y, r4[q].z, r4[q].w};
            int cc[4] = {c4[q].x, c4[q].y, c4[q].z, c4[q].w};
            float vv[4] = {v4[q].x, v4[q].y, v4[q].z, v4[q].w};
            #pragma unroll
            for (int u = 0; u < 4; ++u) {
                int j = q * 4 + u;
                int r = rr[u];
                int b = r / BS;
                myb[j] = b;
                mypack[j] = (cc[u] << 8) | (r - b * BS);
                myval[j] = vv[u];
                atomicAdd(&hist[b], 1);
            }
        }
    } else {
        #pragma unroll
        for (int j = 0; j < 16; ++j) {
            int e = base + j;
            myb[j] = -1;
            if (e < E) {
                int r = rows[e];
                int b = r / BS;
                myb[j] = b;
                mypack[j] = (cols[e] << 8) | (r - b * BS);
                myval[j] = vals[e];
                atomicAdd(&hist[b], 1);
            }
        }
    }
    __syncthreads();

    int h = hist[tid];
    if (h) posBase[tid] = atomicAdd(&bcur[tid], h);
    hist[tid] = 0;   // reuse as local cursor
    __syncthreads();

    #pragma unroll
    for (int j = 0; j < 16; ++j) {
        if (myb[j] >= 0) {
            int p = posBase[myb[j]] + atomicAdd(&hist[myb[j]], 1);
            int2 cv; cv.x = mypack[j]; cv.y = __float_as_int(myval[j]);
            seg[p] = cv;
        }
    }
}

// ---------------- per-bucket LDS sort -> 4B compact entries + offs/rend ------
// Output entry: (col << 16) | bf16(val)   (decode: val = asfloat(p<<16))
__global__ __launch_bounds__(512) void sort_kernel(
    const int* __restrict__ bcur, const int2* __restrict__ seg,
    unsigned* __restrict__ segc,
    int* __restrict__ offs, int* __restrict__ rend)
{
    __shared__ unsigned sorted4[CAP];      // 16 KB
    __shared__ int hist[BS + 1];
    __shared__ int cursor[BS];

    const int b = blockIdx.x;
    const int t = threadIdx.x;
    const int s = b * CAP;
    const int cnt = bcur[b] - s;

    if (t < BS + 1) hist[t] = 0;
    __syncthreads();

    int2 ed[8];
    #pragma unroll
    for (int j = 0; j < 8; ++j) {
        int idx = t + j * 512;
        if (idx < cnt) {
            ed[j] = seg[s + idx];
            atomicAdd(&hist[ed[j].x & 255], 1);
        }
    }
    __syncthreads();

    if (t == 0) {
        int run = 0;
        for (int i = 0; i < BS; ++i) { int c = hist[i]; hist[i] = run; run += c; }
        hist[BS] = run;
    }
    __syncthreads();

    if (t < BS) {
        cursor[t] = hist[t];
        offs[b * BS + t] = s + hist[t];
        rend[b * BS + t] = s + hist[t + 1];
    }
    __syncthreads();

    #pragma unroll
    for (int j = 0; j < 8; ++j) {
        int idx = t + j * 512;
        if (idx < cnt) {
            int pos = atomicAdd(&cursor[ed[j].x & 255], 1);
            unsigned col = ((unsigned)ed[j].x) >> 8;
            sorted4[pos] = (col << 16) | f2bf(__int_as_float(ed[j].y));
        }
    }
    __syncthreads();

    #pragma unroll
    for (int j = 0; j < 8; ++j) {
        int idx = t + j * 512;
        if (idx < cnt) segc[s + idx] = sorted4[idx];
    }
}

// ---------------- SpMM: 4 rows per wave (16-lane groups), 16-deep ------------
// Each 16-lane group owns one row; lane covers 4 channels (ushort4 = 8B).
// Per gather instruction: 4 independent row-lines (512 B) in flight.
__global__ __launch_bounds__(256) void spmm_row_kernel(
    const int* __restrict__ offs, const int* __restrict__ rend,
    const unsigned* __restrict__ segc,
    const __hip_bfloat16* __restrict__ x,
    __hip_bfloat16* __restrict__ yb,      // bf16 out (pass 1)
    float* __restrict__ yf,               // fp32 out (final pass), or null
    const float* __restrict__ bias, int N)
{
    const int tid = threadIdx.x;
    const int lane = tid & 63;
    const int wave = tid >> 6;
    const int grp = lane >> 4;            // 0..3: row within wave
    const int l16 = lane & 15;            // channel group: 4*l16..4*l16+3

    int r = (blockIdx.x * 4 + wave) * 4 + grp;
    const bool rv = r < N;
    const int rc = rv ? r : N - 1;
    const int s = offs[rc];
    const int e = rv ? rend[rc] : s;      // empty range for OOB rows

    int m = e - s;
    m = max(m, __shfl_xor(m, 16));
    m = max(m, __shfl_xor(m, 32));
    const int iters = (m + 15) >> 4;

    const ushort* xp = (const ushort*)x + l16 * 4;

    float4 acc = {0.f, 0.f, 0.f, 0.f};
    for (int it = 0; it < iters; ++it) {
        const int base = s + it * 16;
        unsigned p[16];
        #pragma unroll
        for (int j = 0; j < 16; ++j) {
            int idx = base + j;
            p[j] = segc[idx < e ? idx : s];   // s is always a valid index
        }
        ushort4 xv[16];
        #pragma unroll
        for (int j = 0; j < 16; ++j)
            xv[j] = *(const ushort4*)(xp + (size_t)(p[j] >> 16) * OUT_CH);
        #pragma unroll
        for (int j = 0; j < 16; ++j) {
            int idx = base + j;
            float wv = (idx < e) ? __uint_as_float(p[j] << 16) : 0.f;
            acc.x = fmaf(wv, bf2f(xv[j].x), acc.x);
            acc.y = fmaf(wv, bf2f(xv[j].y), acc.y);
            acc.z = fmaf(wv, bf2f(xv[j].z), acc.z);
            acc.w = fmaf(wv, bf2f(xv[j].w), acc.w);
        }
    }

    if (rv) {
        if (yf) {
            float4 bv = *(const float4*)(bias + l16 * 4);
            float4 o;
            o.x = acc.x + bv.x; o.y = acc.y + bv.y;
            o.z = acc.z + bv.z; o.w = acc.w + bv.w;
            *(float4*)(yf + (size_t)r * OUT_CH + l16 * 4) = o;
        } else {
            ushort4 h;
            h.x = f2bf(acc.x); h.y = f2bf(acc.y);
            h.z = f2bf(acc.z); h.w = f2bf(acc.w);
            *(ushort4*)((ushort*)yb + (size_t)r * OUT_CH + l16 * 4) = h;
        }
    }
}

// ---------------- launch -----------------------------------------------------
static inline size_t align_up(size_t v) { return (v + 255) & ~(size_t)255; }

extern "C" void kernel_launch(void* const* d_in, const int* in_sizes, int n_in,
                              void* d_out, int out_size, void* d_ws, size_t ws_size,
                              hipStream_t stream)
{
    const int*   adj  = (const int*)d_in[0];    // [2,E]
    const float* vals = (const float*)d_in[1];  // [E]
    const float* feat = (const float*)d_in[2];  // [N,512]
    const float* Wm   = (const float*)d_in[3];  // [512,64]
    const float* bias = (const float*)d_in[4];  // [64]

    const int E = in_sizes[1];
    const int N = in_sizes[2] / IN_CH;
    const int* rows  = adj;
    const int* colsI = adj + E;

    char* w = (char*)d_ws;
    size_t o = 0;
    __hip_bfloat16* B0b = (__hip_bfloat16*)(w + o); o += align_up((size_t)N * OUT_CH * 2);
    __hip_bfloat16* Y1b = (__hip_bfloat16*)(w + o); o += align_up((size_t)N * OUT_CH * 2);
    __hip_bfloat16* Wf  = (__hip_bfloat16*)(w + o); o += align_up((size_t)IN_CH * OUT_CH * 2);
    int*      bcur = (int*)     (w + o); o += align_up(NB * sizeof(int));
    int*      offs = (int*)     (w + o); o += align_up((size_t)NB * BS * sizeof(int));
    int*      rend = (int*)     (w + o); o += align_up((size_t)NB * BS * sizeof(int));
    int2*     seg  = (int2*)    (w + o); o += align_up((size_t)NB * CAP * sizeof(int2));
    unsigned* segc = (unsigned*)(w + o); o += align_up((size_t)NB * CAP * sizeof(unsigned));
    (void)ws_size; (void)n_in; (void)out_size;

    // 0. W -> bf16 B-fragments, bcur init
    prep_kernel<<<8, 512, 0, stream>>>(Wm, Wf, bcur);

    // 1. dense projection -> B0b (bf16)
    gemm_kernel<<<(N + 31) / 32, 128, 0, stream>>>(
        feat, (const bf16x8*)Wf, B0b, N);

    // 2. CSR build: fixed-capacity bucket scatter + per-bucket LDS sort
    bucket_scatter_kernel<<<(E + CHUNK - 1) / CHUNK, 512, 0, stream>>>(
        rows, colsI, vals, bcur, seg, E);
    sort_kernel<<<NB, 512, 0, stream>>>(bcur, seg, segc, offs, rend);

    // 3. two propagation rounds (bias fused into the last)
    const int rows_per_block = 16;
    spmm_row_kernel<<<(N + rows_per_block - 1) / rows_per_block, 256, 0, stream>>>(
        offs, rend, segc, B0b, Y1b, nullptr, nullptr, N);
    spmm_row_kernel<<<(N + rows_per_block - 1) / rows_per_block, 256, 0, stream>>>(
        offs, rend, segc, Y1b, nullptr, (float*)d_out, bias, N);
}